// Round 7
// baseline (311.445 us; speedup 1.0000x reference)
//
#include <hip/hip_runtime.h>
#include <cstdint>

#define B_   8
#define C_   256
#define NQ_  1024
#define NK_  4096
#define S_   16
#define H_   8
#define FF_  2048
#define DH_  32
#define BQ_  (B_*NQ_)
#define EPS_ 1e-5f

typedef __bf16 bf16x8 __attribute__((ext_vector_type(8)));
typedef float  f32x4  __attribute__((ext_vector_type(4)));

// ---------------- all weight casts ----------------
struct CvtArgs {
  const float* src[6];
  __bf16* dst[6];
};

// ================= k_prep: one launch for all preprocessing =================
// grid segments:
//   [0, 8192)        key transpose (B,C,NK)->(B,NK,C) bf16
//   [8192, 10240)    query transpose + qpe -> qtok fp32, qinb bf16
//   [10240, 11520)   weight casts (6 tensors)
//   [11520, 11536)   Pk/Pv folded kpe projections
//   [11536, 13584)   box query (1 wave per query, global scan, early break)
#define SEG1 8192
#define SEG2 10240
#define SEG3 11520
#define SEG4 11536
#define NPREP 13584

__global__ __launch_bounds__(256) void k_prep(
    const float* __restrict__ query, const float* __restrict__ key,
    const float* __restrict__ query_pos, const float* __restrict__ key_pos,
    const float* __restrict__ qpe_w, const float* __restrict__ qpe_b,
    const float* __restrict__ k_w, const float* __restrict__ k_b,
    const float* __restrict__ v_w, const float* __restrict__ v_b,
    const float* __restrict__ kpe_w, const float* __restrict__ kpe_b,
    CvtArgs ca,
    __bf16* __restrict__ keyTb, float* __restrict__ qtok,
    __bf16* __restrict__ qinb,
    float4* __restrict__ Pk, float4* __restrict__ Pv,
    int* __restrict__ idxo, int* __restrict__ masko) {
  __shared__ __align__(16) float smem[1248];
  int blk = blockIdx.x, t = threadIdx.x;
  int tx = t & 31, ty = t >> 5;

  if (blk < SEG1) {
    // ---- key transpose: (z, C, NK) -> (z, NK, C) bf16 ----
    float (*tt)[33] = (float(*)[33])smem;
    int x = blk & 127, y = (blk >> 7) & 7, z = blk >> 10;
    int j0 = x * 32, i0 = y * 32;
    const float* inz = key + (size_t)z * C_ * NK_;
    __bf16* outz = keyTb + (size_t)z * NK_ * C_;
#pragma unroll
    for (int r = 0; r < 32; r += 8)
      tt[ty + r][tx] = inz[(size_t)(i0 + ty + r) * NK_ + (j0 + tx)];
    __syncthreads();
#pragma unroll
    for (int r = 0; r < 32; r += 8)
      outz[(size_t)(j0 + ty + r) * C_ + (i0 + tx)] = (__bf16)tt[tx][ty + r];
  } else if (blk < SEG2) {
    // ---- query transpose + qpe ----
    int local = blk - SEG1;
    float (*tt)[33] = (float(*)[33])smem;
    float (*sqp)[6] = (float(*)[6])(smem + 1056);
    int x = local & 31, y = (local >> 5) & 7, z = local >> 8;
    int nq0 = x * 32, c0 = y * 32;
    const float* inz = query + (size_t)z * C_ * NQ_;
#pragma unroll
    for (int r = 0; r < 32; r += 8)
      tt[ty + r][tx] = inz[(size_t)(c0 + ty + r) * NQ_ + (nq0 + tx)];
    if (t < 192)
      sqp[t / 6][t % 6] = query_pos[((size_t)z * NQ_ + nq0 + t / 6) * 6 + (t % 6)];
    int c = c0 + tx;
    float w0 = qpe_w[c * 6 + 0], w1 = qpe_w[c * 6 + 1], w2 = qpe_w[c * 6 + 2];
    float w3 = qpe_w[c * 6 + 3], w4 = qpe_w[c * 6 + 4], w5 = qpe_w[c * 6 + 5];
    float wb = qpe_b[c];
    __syncthreads();
#pragma unroll
    for (int r = 0; r < 32; r += 8) {
      int nql = ty + r;
      size_t row = (size_t)z * NQ_ + nq0 + nql;
      float v = tt[tx][nql];
      float pe = wb + sqp[nql][0] * w0 + sqp[nql][1] * w1 + sqp[nql][2] * w2 +
                 sqp[nql][3] * w3 + sqp[nql][4] * w4 + sqp[nql][5] * w5;
      qtok[row * C_ + c] = v;
      qinb[row * C_ + c] = (__bf16)(v + pe);
    }
  } else if (blk < SEG3) {
    // ---- weight casts ----
    int local = blk - SEG2;
    int idx, base;
    if (local < 64)       { idx = 0; base = local; }
    else if (local < 128) { idx = 1; base = local - 64; }
    else if (local < 192) { idx = 2; base = local - 128; }
    else if (local < 256) { idx = 3; base = local - 192; }
    else if (local < 768) { idx = 4; base = local - 256; }
    else                  { idx = 5; base = local - 768; }
    size_t off = (size_t)base * 1024 + t * 4;
    float4 v = *(const float4*)(ca.src[idx] + off);
    __bf16* o = ca.dst[idx] + off;
    o[0] = (__bf16)v.x; o[1] = (__bf16)v.y; o[2] = (__bf16)v.z; o[3] = (__bf16)v.w;
  } else if (blk < SEG4) {
    // ---- Pk / Pv fold ----
    int local = blk - SEG3;
    int bx = local & 7, bv = local >> 3;
    const float* w  = bv ? v_w : k_w;
    const float* wb = bv ? v_b : k_b;
    float4* P = bv ? Pv : Pk;
    float4 (*red)[8] = (float4(*)[8])smem;
    int nl = t >> 3, ks = (t & 7) * 32;
    int n = bx * 32 + nl;
    const float* wr = w + (size_t)n * C_;
    float p0 = 0.f, p1 = 0.f, p2 = 0.f, pb = 0.f;
#pragma unroll
    for (int k = ks; k < ks + 32; ++k) {
      float wv = wr[k];
      p0 += kpe_w[k * 3 + 0] * wv;
      p1 += kpe_w[k * 3 + 1] * wv;
      p2 += kpe_w[k * 3 + 2] * wv;
      pb += kpe_b[k] * wv;
    }
    red[nl][t & 7] = make_float4(p0, p1, p2, pb);
    __syncthreads();
    if (t < 32) {
      float4 s = red[t][0];
#pragma unroll
      for (int j = 1; j < 8; ++j) {
        float4 r = red[t][j];
        s.x += r.x; s.y += r.y; s.z += r.z; s.w += r.w;
      }
      s.w += wb[bx * 32 + t];
      P[bx * 32 + t] = s;
    }
  } else {
    // ---- box query: 1 wave per query, scan global key_pos, early break ----
    int local = blk - SEG4;
    int lane = t & 63;
    int q = local * 4 + (t >> 6);
    int b = q >> 10;
    const float* kpb = key_pos + (size_t)b * NK_ * 3;
    const float* qp = query_pos + (size_t)q * 6;
    float cx = qp[0], cy = qp[1], cz = qp[2];
    float hx = 0.5f * qp[3], hy = 0.5f * qp[4], hz = 0.5f * qp[5];
    int* iq = idxo + (size_t)q * S_;
    int found = 0;
    for (int ch = 0; ch < NK_ / 64; ++ch) {
      int k = ch * 64 + lane;
      float dx = fabsf(kpb[k * 3 + 0] - cx);
      float dy = fabsf(kpb[k * 3 + 1] - cy);
      float dz = fabsf(kpb[k * 3 + 2] - cz);
      bool inside = (dx <= hx) && (dy <= hy) && (dz <= hz);
      unsigned long long bal = __ballot(inside);
      if (inside) {
        int slot = found + __popcll(bal & ((1ull << lane) - 1ull));
        if (slot < S_) iq[slot] = k;
      }
      found += __popcll(bal);
      if (found >= S_) break;
    }
    if (found > S_) found = S_;
    if (lane < S_) {
      int m = (lane < found) ? 0 : 1;
      if (lane >= found) iq[lane] = 0;
      if (lane == 0) m = 0;
      masko[(size_t)q * S_ + lane] = m;
    }
  }
}

// ============== generalized bf16 MFMA GEMM body ==============
template <int BM, int BN, int RELU, int OUT_BF16>
__device__ __forceinline__ void gemm_body(
    const __bf16* __restrict__ A, const __bf16* __restrict__ Wn,
    const float* __restrict__ bias, void* __restrict__ outp,
    int n0, int m0, int N, int K) {
  constexpr int MI = BM / 32, JN = BN / 32;
  constexpr int AIT = (BM * 64) / 2048, BIT = (BN * 64) / 2048;
  __shared__ __bf16 As[BM][72];
  __shared__ __bf16 Bs[BN][72];
  int t = threadIdx.x;
  int lane = t & 63, w = t >> 6;
  int lane16 = lane & 15, quad = lane >> 4;
  int wm = (w & 1) * (BM / 2), wn = (w >> 1) * (BN / 2);

  f32x4 acc[MI][JN];
#pragma unroll
  for (int i = 0; i < MI; ++i)
#pragma unroll
    for (int j = 0; j < JN; ++j) acc[i][j] = (f32x4){0.f, 0.f, 0.f, 0.f};

  for (int k0 = 0; k0 < K; k0 += 64) {
#pragma unroll
    for (int i = 0; i < AIT; ++i) {
      int ii = i * 256 + t;
      int m = ii >> 3, kc = (ii & 7) * 8;
      *(bf16x8*)&As[m][kc] = *(const bf16x8*)&A[(size_t)(m0 + m) * K + k0 + kc];
    }
#pragma unroll
    for (int i = 0; i < BIT; ++i) {
      int ii = i * 256 + t;
      int m = ii >> 3, kc = (ii & 7) * 8;
      *(bf16x8*)&Bs[m][kc] = *(const bf16x8*)&Wn[(size_t)(n0 + m) * K + k0 + kc];
    }
    __syncthreads();
#pragma unroll
    for (int kk = 0; kk < 64; kk += 32) {
      bf16x8 af[MI], bfr[JN];
#pragma unroll
      for (int i = 0; i < MI; ++i)
        af[i] = *(const bf16x8*)&As[wm + i * 16 + lane16][kk + quad * 8];
#pragma unroll
      for (int j = 0; j < JN; ++j)
        bfr[j] = *(const bf16x8*)&Bs[wn + j * 16 + lane16][kk + quad * 8];
#pragma unroll
      for (int i = 0; i < MI; ++i)
#pragma unroll
        for (int j = 0; j < JN; ++j)
          acc[i][j] = __builtin_amdgcn_mfma_f32_16x16x32_bf16(af[i], bfr[j], acc[i][j], 0, 0, 0);
    }
    __syncthreads();
  }

#pragma unroll
  for (int j = 0; j < JN; ++j) {
    int col = n0 + wn + j * 16 + lane16;
    float bv = bias ? bias[col] : 0.f;
#pragma unroll
    for (int i = 0; i < MI; ++i) {
#pragma unroll
      for (int r = 0; r < 4; ++r) {
        int row = m0 + wm + i * 16 + quad * 4 + r;
        float v = acc[i][j][r] + bv;
        if (RELU) v = fmaxf(v, 0.f);
        if (OUT_BF16)
          ((__bf16*)outp)[(size_t)row * N + col] = (__bf16)v;
        else
          ((float*)outp)[(size_t)row * N + col] = v;
      }
    }
  }
}

template <int BM, int BN, int RELU, int OUT_BF16>
__global__ __launch_bounds__(256) void k_gemm(
    const __bf16* __restrict__ A, const __bf16* __restrict__ Wn,
    const float* __restrict__ bias, void* __restrict__ outp, int N, int K) {
  gemm_body<BM, BN, RELU, OUT_BF16>(A, Wn, bias, outp,
                                    blockIdx.x * BN, blockIdx.y * BM, N, K);
}

// ---- merged khv GEMM (1024 blocks) + qh GEMM (128 blocks) ----
__global__ __launch_bounds__(256) void k_gemm2(
    const __bf16* __restrict__ keyTb, const __bf16* __restrict__ kvwb,
    __bf16* __restrict__ khvbuf,
    const __bf16* __restrict__ qinb, const __bf16* __restrict__ qwb,
    const float* __restrict__ q_b, __bf16* __restrict__ qhb) {
  int blk = blockIdx.x;
  const __bf16 *A, *Wn; const float* bias; __bf16* outp; int n0, m0, N;
  if (blk < 1024) {
    A = keyTb; Wn = kvwb; bias = nullptr; outp = khvbuf;
    n0 = (blk & 3) * 128; m0 = (blk >> 2) * 128; N = 512;
  } else {
    int l = blk - 1024;
    A = qinb; Wn = qwb; bias = q_b; outp = qhb;
    n0 = (l & 1) * 128; m0 = (l >> 1) * 128; N = 256;
  }
  gemm_body<128, 128, 0, 1>(A, Wn, bias, outp, n0, m0, N, 256);
}

// ---- fused attention: gather kh|vh, inline qpk reduce, scores, softmax,
//      PV + folded Pv/pgx. one block per query token.
__global__ __launch_bounds__(256) void k_attnf(
    const __bf16* __restrict__ khv,       // (B*NK, 512): [kh|vh] per key
    const float* __restrict__ key_pos,    // (B, NK, 3)
    const float* __restrict__ query_pos,  // (BQ, 6)
    const int* __restrict__ idx,          // (BQ, S)
    const int* __restrict__ maskb,        // (BQ, S)
    const __bf16* __restrict__ qhb,       // (BQ, C)
    const float4* __restrict__ Pk,        // (C)
    const float4* __restrict__ Pv,        // (C)
    __bf16* __restrict__ aob) {           // (BQ, C)
  __shared__ __bf16 kvs[S_][520];
  __shared__ float qrow[C_];
  __shared__ float sc[H_][S_];
  __shared__ float pw[H_][S_];
  __shared__ float4 gx4[S_];
  __shared__ float4 pgxs[H_];
  __shared__ float4 qpks[H_];
  __shared__ int srow[S_], smask[S_];
  int bq = blockIdx.x, b = bq >> 10, t = threadIdx.x;

  if (t < S_) {
    int k = idx[(size_t)bq * S_ + t];
    srow[t] = b * NK_ + k;
    smask[t] = maskb[(size_t)bq * S_ + t];
    const float* kpp = key_pos + ((size_t)b * NK_ + k) * 3;
    const float* qp  = query_pos + (size_t)bq * 6;
    gx4[t] = make_float4(kpp[0] - qp[0], kpp[1] - qp[1], kpp[2] - qp[2], 1.f);
  }
  float qv_t = (float)qhb[(size_t)bq * C_ + t];
  qrow[t] = qv_t;
  {  // inline qpk: per-head reduce of qrow[t]*Pk[t] over 32 lanes
    float4 p = Pk[t];
    p.x *= qv_t; p.y *= qv_t; p.z *= qv_t; p.w *= qv_t;
#pragma unroll
    for (int off = 16; off >= 1; off >>= 1) {
      p.x += __shfl_xor(p.x, off);
      p.y += __shfl_xor(p.y, off);
      p.z += __shfl_xor(p.z, off);
      p.w += __shfl_xor(p.w, off);
    }
    if ((t & 31) == 0) {
      const float s = 0.17677669529663687f;
      qpks[t >> 5] = make_float4(p.x * s, p.y * s, p.z * s, p.w * s);
    }
  }
  __syncthreads();
  {  // gather khv rows: 16 rows x 1KB contiguous
    int s = t >> 4, c0 = (t & 15) * 32;
    const __bf16* src = khv + (size_t)srow[s] * 512 + c0;
    *(bf16x8*)&kvs[s][c0]      = *(const bf16x8*)&src[0];
    *(bf16x8*)&kvs[s][c0 + 8]  = *(const bf16x8*)&src[8];
    *(bf16x8*)&kvs[s][c0 + 16] = *(const bf16x8*)&src[16];
    *(bf16x8*)&kvs[s][c0 + 24] = *(const bf16x8*)&src[24];
  }
  __syncthreads();
  if (t < H_ * S_) {  // scores: 32-MAC per-head dot
    int h = t >> 4, s = t & (S_ - 1);
    float d = 0.f;
#pragma unroll
    for (int c0 = 0; c0 < 32; c0 += 8) {
      bf16x8 xv = *(const bf16x8*)&kvs[s][h * 32 + c0];
#pragma unroll
      for (int j = 0; j < 8; ++j) d += qrow[h * 32 + c0 + j] * (float)xv[j];
    }
    d *= 0.17677669529663687f;
    float4 g = gx4[s];
    float4 pk = qpks[h];
    d += g.x * pk.x + g.y * pk.y + g.z * pk.z + pk.w;
    if (smask[s]) d = -1e30f;
    sc[h][s] = d;
  }
  __syncthreads();
  if (t < H_) {  // softmax + pgx
    float mx = -3.4e38f;
#pragma unroll
    for (int s = 0; s < S_; ++s) mx = fmaxf(mx, sc[t][s]);
    float e[S_], sum = 0.f;
#pragma unroll
    for (int s = 0; s < S_; ++s) { e[s] = expf(sc[t][s] - mx); sum += e[s]; }
    float inv = 1.f / sum;
    float gxx = 0.f, gyy = 0.f, gzz = 0.f;
#pragma unroll
    for (int s = 0; s < S_; ++s) {
      float p = e[s] * inv;
      pw[t][s] = p;
      float4 g = gx4[s];
      gxx += p * g.x; gyy += p * g.y; gzz += p * g.z;
    }
    pgxs[t] = make_float4(gxx, gyy, gzz, 1.f);
  }
  __syncthreads();
  {  // PV
    int h = t >> 5;
    float a = 0.f;
#pragma unroll
    for (int s = 0; s < S_; ++s) a += pw[h][s] * (float)kvs[s][256 + t];
    float4 pv = Pv[t];
    float4 g = pgxs[h];
    a += g.x * pv.x + g.y * pv.y + g.z * pv.z + pv.w;
    aob[(size_t)bq * C_ + t] = (__bf16)a;
  }
}

// ---------------- LN1: out = LN(xa + xb)*g + b, fp32 + bf16 copies ----------
__global__ __launch_bounds__(256) void k_ln1(const float* __restrict__ xa,
                                             const float* __restrict__ xb,
                                             const float* __restrict__ g,
                                             const float* __restrict__ bb,
                                             float* __restrict__ outf,
                                             __bf16* __restrict__ outb) {
  int wid = (blockIdx.x * 256 + threadIdx.x) >> 6;
  int lane = threadIdx.x & 63;
  float4 va = *(const float4*)(xa + (size_t)wid * C_ + lane * 4);
  float4 vb = *(const float4*)(xb + (size_t)wid * C_ + lane * 4);
  float x0 = va.x + vb.x, x1 = va.y + vb.y, x2 = va.z + vb.z, x3 = va.w + vb.w;
  float s = x0 + x1 + x2 + x3;
#pragma unroll
  for (int off = 32; off >= 1; off >>= 1) s += __shfl_xor(s, off);
  float mean = s * (1.f / C_);
  float d0 = x0 - mean, d1 = x1 - mean, d2 = x2 - mean, d3 = x3 - mean;
  float v = d0 * d0 + d1 * d1 + d2 * d2 + d3 * d3;
#pragma unroll
  for (int off = 32; off >= 1; off >>= 1) v += __shfl_xor(v, off);
  float inv = 1.f / sqrtf(v * (1.f / C_) + EPS_);
  float4 g4 = *(const float4*)(g + lane * 4);
  float4 b4 = *(const float4*)(bb + lane * 4);
  float4 o;
  o.x = d0 * inv * g4.x + b4.x;
  o.y = d1 * inv * g4.y + b4.y;
  o.z = d2 * inv * g4.z + b4.z;
  o.w = d3 * inv * g4.w + b4.w;
  *(float4*)(outf + (size_t)wid * C_ + lane * 4) = o;
  __bf16* ob = outb + (size_t)wid * C_ + lane * 4;
  ob[0] = (__bf16)o.x; ob[1] = (__bf16)o.y; ob[2] = (__bf16)o.z; ob[3] = (__bf16)o.w;
}

// ---- fused LN2 + output transpose: out(B,C,NQ) = LN(x1+ff2)^T ------------
__global__ __launch_bounds__(256) void k_lnt(const float* __restrict__ xa,
                                             const float* __restrict__ xb,
                                             const float* __restrict__ g,
                                             const float* __restrict__ bb,
                                             float* __restrict__ out) {
  __shared__ float buf[32][257];
  int z = blockIdx.y, nq0 = blockIdx.x * 32;
  int t = threadIdx.x;
  int w = t >> 6, lane = t & 63;
  float4 g4 = *(const float4*)(g + lane * 4);
  float4 b4 = *(const float4*)(bb + lane * 4);
#pragma unroll
  for (int rr = 0; rr < 8; ++rr) {
    int row = w * 8 + rr;
    size_t base = ((size_t)z * NQ_ + nq0 + row) * C_ + lane * 4;
    float4 va = *(const float4*)(xa + base);
    float4 vb = *(const float4*)(xb + base);
    float x0 = va.x + vb.x, x1 = va.y + vb.y, x2 = va.z + vb.z, x3 = va.w + vb.w;
    float s = x0 + x1 + x2 + x3;
#pragma unroll
    for (int off = 32; off >= 1; off >>= 1) s += __shfl_xor(s, off);
    float mean = s * (1.f / C_);
    float d0 = x0 - mean, d1 = x1 - mean, d2 = x2 - mean, d3 = x3 - mean;
    float v = d0 * d0 + d1 * d1 + d2 * d2 + d3 * d3;
#pragma unroll
    for (int off = 32; off >= 1; off >>= 1) v += __shfl_xor(v, off);
    float inv = 1.f / sqrtf(v * (1.f / C_) + EPS_);
    buf[row][lane * 4 + 0] = d0 * inv * g4.x + b4.x;
    buf[row][lane * 4 + 1] = d1 * inv * g4.y + b4.y;
    buf[row][lane * 4 + 2] = d2 * inv * g4.z + b4.z;
    buf[row][lane * 4 + 3] = d3 * inv * g4.w + b4.w;
  }
  __syncthreads();
  int tx = t & 31, ty = t >> 5;
#pragma unroll
  for (int ci = 0; ci < 32; ++ci) {
    int c = ci * 8 + ty;
    out[((size_t)z * C_ + c) * NQ_ + nq0 + tx] = buf[tx][c];
  }
}

extern "C" void kernel_launch(void* const* d_in, const int* in_sizes, int n_in,
                              void* d_out, int out_size, void* d_ws, size_t ws_size,
                              hipStream_t stream) {
  const float* query     = (const float*)d_in[0];
  const float* key       = (const float*)d_in[1];
  const float* query_pos = (const float*)d_in[2];
  const float* key_pos   = (const float*)d_in[3];
  const float* q_w = (const float*)d_in[4];  const float* q_b = (const float*)d_in[5];
  const float* k_w = (const float*)d_in[6];  const float* k_b = (const float*)d_in[7];
  const float* v_w = (const float*)d_in[8];  const float* v_b = (const float*)d_in[9];
  const float* o_w = (const float*)d_in[10]; const float* o_b = (const float*)d_in[11];
  const float* lin1_w = (const float*)d_in[12]; const float* lin1_b = (const float*)d_in[13];
  const float* lin2_w = (const float*)d_in[14]; const float* lin2_b = (const float*)d_in[15];
  const float* n1_g = (const float*)d_in[16]; const float* n1_b = (const float*)d_in[17];
  const float* n2_g = (const float*)d_in[18]; const float* n2_b = (const float*)d_in[19];
  const float* qpe_w = (const float*)d_in[20]; const float* qpe_b = (const float*)d_in[21];
  const float* kpe_w = (const float*)d_in[22]; const float* kpe_b = (const float*)d_in[23];
  float* out = (float*)d_out;

  const size_t BQc = (size_t)BQ_ * C_;
  float* w = (float*)d_ws;
  size_t o = 0;
  // ---- workspace carve (~100 MB) ----
  __bf16* keyTb = (__bf16*)(w + o); o += (size_t)B_ * NK_ * C_ / 2;   // 16.8 MB
  float* qtok  = w + o; o += BQc;
  float* x1    = w + o; o += BQc;
  float* attno = w + o; o += BQc;                                     // ff2o overlay
  __bf16* khvbuf = (__bf16*)(w + o); o += (size_t)B_ * NK_ * 512 / 2; // 33.5 MB; ff1b overlay
  __bf16* qinb = (__bf16*)(w + o); o += BQc / 2;
  __bf16* qhb  = (__bf16*)(w + o); o += BQc / 2;
  __bf16* aob  = (__bf16*)(w + o); o += BQc / 2;
  __bf16* x1b  = (__bf16*)(w + o); o += BQc / 2;
  __bf16* qwb  = (__bf16*)(w + o); o += (size_t)C_ * C_ / 2;
  __bf16* kvwb = (__bf16*)(w + o); o += (size_t)C_ * C_;              // (512,256) = k_w ++ v_w
  __bf16* owb  = (__bf16*)(w + o); o += (size_t)C_ * C_ / 2;
  __bf16* l1b  = (__bf16*)(w + o); o += (size_t)C_ * FF_ / 2;
  __bf16* l2b  = (__bf16*)(w + o); o += (size_t)C_ * FF_ / 2;
  float4* Pk   = (float4*)(w + o); o += C_ * 4;
  float4* Pv   = (float4*)(w + o); o += C_ * 4;
  int* idxb  = (int*)(w + o); o += (size_t)BQ_ * S_;
  int* maskb = (int*)(w + o); o += (size_t)BQ_ * S_;
  __bf16* ff1b = khvbuf;    // khv dead after attnf
  float* ff2o  = attno;     // attno dead after LN1

  // 1. all preprocessing in one launch
  CvtArgs ca;
  ca.src[0] = q_w; ca.dst[0] = qwb;
  ca.src[1] = k_w; ca.dst[1] = kvwb;
  ca.src[2] = v_w; ca.dst[2] = kvwb + (size_t)C_ * C_;
  ca.src[3] = o_w; ca.dst[3] = owb;
  ca.src[4] = lin1_w; ca.dst[4] = l1b;
  ca.src[5] = lin2_w; ca.dst[5] = l2b;
  k_prep<<<NPREP, 256, 0, stream>>>(query, key, query_pos, key_pos,
                                    qpe_w, qpe_b, k_w, k_b, v_w, v_b,
                                    kpe_w, kpe_b, ca,
                                    keyTb, qtok, qinb, Pk, Pv, idxb, maskb);
  // 2. khv = key_feat @ [k_w|v_w]^T (per unique key)  +  qh = qin @ q_w.T + q_b
  k_gemm2<<<1024 + 128, 256, 0, stream>>>(keyTb, kvwb, khvbuf, qinb, qwb, q_b, qhb);
  // 3. fused attention
  k_attnf<<<BQ_, 256, 0, stream>>>(khvbuf, key_pos, query_pos, idxb, maskb,
                                   qhb, Pk, Pv, aob);
  // 4. o projection (fp32 out), BM=64/BN=64 -> 512 blocks (2/CU)
  k_gemm<64, 64, 0, 0><<<dim3(C_ / 64, BQ_ / 64), 256, 0, stream>>>(
      aob, owb, o_b, attno, C_, C_);
  // 5. x1 = LN(qtok + attno), fp32 + bf16
  k_ln1<<<BQ_ / 4, 256, 0, stream>>>(qtok, attno, n1_g, n1_b, x1, x1b);
  // 6. ff1(bf16) = relu(x1 @ lin1.T + b)   [overlays khvbuf]
  k_gemm<128, 128, 1, 1><<<dim3(FF_ / 128, BQ_ / 128), 256, 0, stream>>>(
      x1b, l1b, lin1_b, ff1b, FF_, C_);
  // 7. ff2(fp32) = ff1 @ lin2.T + b        [overlays attno], 512 blocks
  k_gemm<64, 64, 0, 0><<<dim3(C_ / 64, BQ_ / 64), 256, 0, stream>>>(
      ff1b, l2b, lin2_b, ff2o, C_, FF_);
  // 8. out = transpose(LN(x1 + ff2))
  k_lnt<<<dim3(NQ_ / 32, B_), 256, 0, stream>>>(x1, ff2o, n2_g, n2_b, out);
}

// Round 8
// 273.819 us; speedup vs baseline: 1.1374x; 1.1374x over previous
//
#include <hip/hip_runtime.h>
#include <cstdint>

#define B_   8
#define C_   256
#define NQ_  1024
#define NK_  4096
#define S_   16
#define H_   8
#define FF_  2048
#define DH_  32
#define BQ_  (B_*NQ_)
#define EPS_ 1e-5f
#define KS_  8     // ff2 split-K factor (k-chunk = 2048/8 = 256)

typedef __bf16 bf16x8 __attribute__((ext_vector_type(8)));
typedef __bf16 bf16x4 __attribute__((ext_vector_type(4)));
typedef float  f32x4  __attribute__((ext_vector_type(4)));

// ---------------- all weight casts ----------------
struct CvtArgs {
  const float* src[6];
  __bf16* dst[6];
};

// ================= k_prep: one launch for all preprocessing =================
#define SEG1 8192
#define SEG2 10240
#define SEG3 11520
#define SEG4 11536
#define NPREP 13584

__global__ __launch_bounds__(256) void k_prep(
    const float* __restrict__ query, const float* __restrict__ key,
    const float* __restrict__ query_pos, const float* __restrict__ key_pos,
    const float* __restrict__ qpe_w, const float* __restrict__ qpe_b,
    const float* __restrict__ k_w, const float* __restrict__ k_b,
    const float* __restrict__ v_w, const float* __restrict__ v_b,
    const float* __restrict__ kpe_w, const float* __restrict__ kpe_b,
    CvtArgs ca,
    __bf16* __restrict__ keyTb, float* __restrict__ qtok,
    __bf16* __restrict__ qinb,
    float4* __restrict__ Pk, float4* __restrict__ Pv,
    int* __restrict__ idxo, int* __restrict__ masko) {
  __shared__ __align__(16) float smem[1248];
  int blk = blockIdx.x, t = threadIdx.x;
  int tx = t & 31, ty = t >> 5;

  if (blk < SEG1) {
    // ---- key transpose: (z, C, NK) -> (z, NK, C) bf16 ----
    float (*tt)[33] = (float(*)[33])smem;
    int x = blk & 127, y = (blk >> 7) & 7, z = blk >> 10;
    int j0 = x * 32, i0 = y * 32;
    const float* inz = key + (size_t)z * C_ * NK_;
    __bf16* outz = keyTb + (size_t)z * NK_ * C_;
#pragma unroll
    for (int r = 0; r < 32; r += 8)
      tt[ty + r][tx] = inz[(size_t)(i0 + ty + r) * NK_ + (j0 + tx)];
    __syncthreads();
#pragma unroll
    for (int r = 0; r < 32; r += 8)
      outz[(size_t)(j0 + ty + r) * C_ + (i0 + tx)] = (__bf16)tt[tx][ty + r];
  } else if (blk < SEG2) {
    // ---- query transpose + qpe ----
    int local = blk - SEG1;
    float (*tt)[33] = (float(*)[33])smem;
    float (*sqp)[6] = (float(*)[6])(smem + 1056);
    int x = local & 31, y = (local >> 5) & 7, z = local >> 8;
    int nq0 = x * 32, c0 = y * 32;
    const float* inz = query + (size_t)z * C_ * NQ_;
#pragma unroll
    for (int r = 0; r < 32; r += 8)
      tt[ty + r][tx] = inz[(size_t)(c0 + ty + r) * NQ_ + (nq0 + tx)];
    if (t < 192)
      sqp[t / 6][t % 6] = query_pos[((size_t)z * NQ_ + nq0 + t / 6) * 6 + (t % 6)];
    int c = c0 + tx;
    float w0 = qpe_w[c * 6 + 0], w1 = qpe_w[c * 6 + 1], w2 = qpe_w[c * 6 + 2];
    float w3 = qpe_w[c * 6 + 3], w4 = qpe_w[c * 6 + 4], w5 = qpe_w[c * 6 + 5];
    float wb = qpe_b[c];
    __syncthreads();
#pragma unroll
    for (int r = 0; r < 32; r += 8) {
      int nql = ty + r;
      size_t row = (size_t)z * NQ_ + nq0 + nql;
      float v = tt[tx][nql];
      float pe = wb + sqp[nql][0] * w0 + sqp[nql][1] * w1 + sqp[nql][2] * w2 +
                 sqp[nql][3] * w3 + sqp[nql][4] * w4 + sqp[nql][5] * w5;
      qtok[row * C_ + c] = v;
      qinb[row * C_ + c] = (__bf16)(v + pe);
    }
  } else if (blk < SEG3) {
    // ---- weight casts ----
    int local = blk - SEG2;
    int idx, base;
    if (local < 64)       { idx = 0; base = local; }
    else if (local < 128) { idx = 1; base = local - 64; }
    else if (local < 192) { idx = 2; base = local - 128; }
    else if (local < 256) { idx = 3; base = local - 192; }
    else if (local < 768) { idx = 4; base = local - 256; }
    else                  { idx = 5; base = local - 768; }
    size_t off = (size_t)base * 1024 + t * 4;
    float4 v = *(const float4*)(ca.src[idx] + off);
    __bf16* o = ca.dst[idx] + off;
    o[0] = (__bf16)v.x; o[1] = (__bf16)v.y; o[2] = (__bf16)v.z; o[3] = (__bf16)v.w;
  } else if (blk < SEG4) {
    // ---- Pk / Pv fold ----
    int local = blk - SEG3;
    int bx = local & 7, bv = local >> 3;
    const float* w  = bv ? v_w : k_w;
    const float* wb = bv ? v_b : k_b;
    float4* P = bv ? Pv : Pk;
    float4 (*red)[8] = (float4(*)[8])smem;
    int nl = t >> 3, ks = (t & 7) * 32;
    int n = bx * 32 + nl;
    const float* wr = w + (size_t)n * C_;
    float p0 = 0.f, p1 = 0.f, p2 = 0.f, pb = 0.f;
#pragma unroll
    for (int k = ks; k < ks + 32; ++k) {
      float wv = wr[k];
      p0 += kpe_w[k * 3 + 0] * wv;
      p1 += kpe_w[k * 3 + 1] * wv;
      p2 += kpe_w[k * 3 + 2] * wv;
      pb += kpe_b[k] * wv;
    }
    red[nl][t & 7] = make_float4(p0, p1, p2, pb);
    __syncthreads();
    if (t < 32) {
      float4 s = red[t][0];
#pragma unroll
      for (int j = 1; j < 8; ++j) {
        float4 r = red[t][j];
        s.x += r.x; s.y += r.y; s.z += r.z; s.w += r.w;
      }
      s.w += wb[bx * 32 + t];
      P[bx * 32 + t] = s;
    }
  } else {
    // ---- box query: 1 wave per query, scan global key_pos, early break ----
    int local = blk - SEG4;
    int lane = t & 63;
    int q = local * 4 + (t >> 6);
    int b = q >> 10;
    const float* kpb = key_pos + (size_t)b * NK_ * 3;
    const float* qp = query_pos + (size_t)q * 6;
    float cx = qp[0], cy = qp[1], cz = qp[2];
    float hx = 0.5f * qp[3], hy = 0.5f * qp[4], hz = 0.5f * qp[5];
    int* iq = idxo + (size_t)q * S_;
    int found = 0;
    for (int ch = 0; ch < NK_ / 64; ++ch) {
      int k = ch * 64 + lane;
      float dx = fabsf(kpb[k * 3 + 0] - cx);
      float dy = fabsf(kpb[k * 3 + 1] - cy);
      float dz = fabsf(kpb[k * 3 + 2] - cz);
      bool inside = (dx <= hx) && (dy <= hy) && (dz <= hz);
      unsigned long long bal = __ballot(inside);
      if (inside) {
        int slot = found + __popcll(bal & ((1ull << lane) - 1ull));
        if (slot < S_) iq[slot] = k;
      }
      found += __popcll(bal);
      if (found >= S_) break;
    }
    if (found > S_) found = S_;
    if (lane < S_) {
      int m = (lane < found) ? 0 : 1;
      if (lane >= found) iq[lane] = 0;
      if (lane == 0) m = 0;
      masko[(size_t)q * S_ + lane] = m;
    }
  }
}

// ============== generalized bf16 MFMA GEMM body (k-range) ==============
template <int BM, int BN, int RELU, int OUT_BF16>
__device__ __forceinline__ void gemm_body(
    const __bf16* __restrict__ A, const __bf16* __restrict__ Wn,
    const float* __restrict__ bias, void* __restrict__ outp,
    int n0, int m0, int N, int K, int kbeg, int kend) {
  constexpr int MI = BM / 32, JN = BN / 32;
  constexpr int AIT = (BM * 64) / 2048, BIT = (BN * 64) / 2048;
  __shared__ __bf16 As[BM][72];
  __shared__ __bf16 Bs[BN][72];
  int t = threadIdx.x;
  int lane = t & 63, w = t >> 6;
  int lane16 = lane & 15, quad = lane >> 4;
  int wm = (w & 1) * (BM / 2), wn = (w >> 1) * (BN / 2);

  f32x4 acc[MI][JN];
#pragma unroll
  for (int i = 0; i < MI; ++i)
#pragma unroll
    for (int j = 0; j < JN; ++j) acc[i][j] = (f32x4){0.f, 0.f, 0.f, 0.f};

  for (int k0 = kbeg; k0 < kend; k0 += 64) {
#pragma unroll
    for (int i = 0; i < AIT; ++i) {
      int ii = i * 256 + t;
      int m = ii >> 3, kc = (ii & 7) * 8;
      *(bf16x8*)&As[m][kc] = *(const bf16x8*)&A[(size_t)(m0 + m) * K + k0 + kc];
    }
#pragma unroll
    for (int i = 0; i < BIT; ++i) {
      int ii = i * 256 + t;
      int m = ii >> 3, kc = (ii & 7) * 8;
      *(bf16x8*)&Bs[m][kc] = *(const bf16x8*)&Wn[(size_t)(n0 + m) * K + k0 + kc];
    }
    __syncthreads();
#pragma unroll
    for (int kk = 0; kk < 64; kk += 32) {
      bf16x8 af[MI], bfr[JN];
#pragma unroll
      for (int i = 0; i < MI; ++i)
        af[i] = *(const bf16x8*)&As[wm + i * 16 + lane16][kk + quad * 8];
#pragma unroll
      for (int j = 0; j < JN; ++j)
        bfr[j] = *(const bf16x8*)&Bs[wn + j * 16 + lane16][kk + quad * 8];
#pragma unroll
      for (int i = 0; i < MI; ++i)
#pragma unroll
        for (int j = 0; j < JN; ++j)
          acc[i][j] = __builtin_amdgcn_mfma_f32_16x16x32_bf16(af[i], bfr[j], acc[i][j], 0, 0, 0);
    }
    __syncthreads();
  }

#pragma unroll
  for (int j = 0; j < JN; ++j) {
    int col = n0 + wn + j * 16 + lane16;
    float bv = bias ? bias[col] : 0.f;
#pragma unroll
    for (int i = 0; i < MI; ++i) {
#pragma unroll
      for (int r = 0; r < 4; ++r) {
        int row = m0 + wm + i * 16 + quad * 4 + r;
        float v = acc[i][j][r] + bv;
        if (RELU) v = fmaxf(v, 0.f);
        if (OUT_BF16)
          ((__bf16*)outp)[(size_t)row * N + col] = (__bf16)v;
        else
          ((float*)outp)[(size_t)row * N + col] = v;
      }
    }
  }
}

template <int BM, int BN, int RELU, int OUT_BF16>
__global__ __launch_bounds__(256) void k_gemm(
    const __bf16* __restrict__ A, const __bf16* __restrict__ Wn,
    const float* __restrict__ bias, void* __restrict__ outp, int N, int K) {
  gemm_body<BM, BN, RELU, OUT_BF16>(A, Wn, bias, outp,
                                    blockIdx.x * BN, blockIdx.y * BM, N, K, 0, K);
}

// ---- split-K ff2: partials[ks][BQ][C] bf16, no bias (added in k_lnt) ----
__global__ __launch_bounds__(256) void k_gemmsk(
    const __bf16* __restrict__ A, const __bf16* __restrict__ Wn,
    __bf16* __restrict__ partials) {
  int ks = blockIdx.z;
  int kbeg = ks * (FF_ / KS_), kend = kbeg + FF_ / KS_;
  gemm_body<128, 128, 0, 1>(A, Wn, nullptr,
                            partials + (size_t)ks * BQ_ * C_,
                            blockIdx.x * 128, blockIdx.y * 128, C_, FF_, kbeg, kend);
}

// ---- merged khv GEMM (1024 blocks) + qh GEMM (128 blocks) ----
__global__ __launch_bounds__(256) void k_gemm2(
    const __bf16* __restrict__ keyTb, const __bf16* __restrict__ kvwb,
    __bf16* __restrict__ khvbuf,
    const __bf16* __restrict__ qinb, const __bf16* __restrict__ qwb,
    const float* __restrict__ q_b, __bf16* __restrict__ qhb) {
  int blk = blockIdx.x;
  const __bf16 *A, *Wn; const float* bias; __bf16* outp; int n0, m0, N;
  if (blk < 1024) {
    A = keyTb; Wn = kvwb; bias = nullptr; outp = khvbuf;
    n0 = (blk & 3) * 128; m0 = (blk >> 2) * 128; N = 512;
  } else {
    int l = blk - 1024;
    A = qinb; Wn = qwb; bias = q_b; outp = qhb;
    n0 = (l & 1) * 128; m0 = (l >> 1) * 128; N = 256;
  }
  gemm_body<128, 128, 0, 1>(A, Wn, bias, outp, n0, m0, N, 256, 0, 256);
}

// ---- fused attention: gather kh|vh, inline qpk reduce, scores, softmax,
//      PV + folded Pv/pgx. one block per query token.
__global__ __launch_bounds__(256) void k_attnf(
    const __bf16* __restrict__ khv,       // (B*NK, 512): [kh|vh] per key
    const float* __restrict__ key_pos,    // (B, NK, 3)
    const float* __restrict__ query_pos,  // (BQ, 6)
    const int* __restrict__ idx,          // (BQ, S)
    const int* __restrict__ maskb,        // (BQ, S)
    const __bf16* __restrict__ qhb,       // (BQ, C)
    const float4* __restrict__ Pk,        // (C)
    const float4* __restrict__ Pv,        // (C)
    __bf16* __restrict__ aob) {           // (BQ, C)
  __shared__ __bf16 kvs[S_][520];
  __shared__ float qrow[C_];
  __shared__ float sc[H_][S_];
  __shared__ float pw[H_][S_];
  __shared__ float4 gx4[S_];
  __shared__ float4 pgxs[H_];
  __shared__ float4 qpks[H_];
  __shared__ int srow[S_], smask[S_];
  int bq = blockIdx.x, b = bq >> 10, t = threadIdx.x;

  if (t < S_) {
    int k = idx[(size_t)bq * S_ + t];
    srow[t] = b * NK_ + k;
    smask[t] = maskb[(size_t)bq * S_ + t];
    const float* kpp = key_pos + ((size_t)b * NK_ + k) * 3;
    const float* qp  = query_pos + (size_t)bq * 6;
    gx4[t] = make_float4(kpp[0] - qp[0], kpp[1] - qp[1], kpp[2] - qp[2], 1.f);
  }
  float qv_t = (float)qhb[(size_t)bq * C_ + t];
  qrow[t] = qv_t;
  {  // inline qpk: per-head reduce of qrow[t]*Pk[t] over 32 lanes
    float4 p = Pk[t];
    p.x *= qv_t; p.y *= qv_t; p.z *= qv_t; p.w *= qv_t;
#pragma unroll
    for (int off = 16; off >= 1; off >>= 1) {
      p.x += __shfl_xor(p.x, off);
      p.y += __shfl_xor(p.y, off);
      p.z += __shfl_xor(p.z, off);
      p.w += __shfl_xor(p.w, off);
    }
    if ((t & 31) == 0) {
      const float s = 0.17677669529663687f;
      qpks[t >> 5] = make_float4(p.x * s, p.y * s, p.z * s, p.w * s);
    }
  }
  __syncthreads();
  {  // gather khv rows: 16 rows x 1KB contiguous
    int s = t >> 4, c0 = (t & 15) * 32;
    const __bf16* src = khv + (size_t)srow[s] * 512 + c0;
    *(bf16x8*)&kvs[s][c0]      = *(const bf16x8*)&src[0];
    *(bf16x8*)&kvs[s][c0 + 8]  = *(const bf16x8*)&src[8];
    *(bf16x8*)&kvs[s][c0 + 16] = *(const bf16x8*)&src[16];
    *(bf16x8*)&kvs[s][c0 + 24] = *(const bf16x8*)&src[24];
  }
  __syncthreads();
  if (t < H_ * S_) {  // scores: 32-MAC per-head dot
    int h = t >> 4, s = t & (S_ - 1);
    float d = 0.f;
#pragma unroll
    for (int c0 = 0; c0 < 32; c0 += 8) {
      bf16x8 xv = *(const bf16x8*)&kvs[s][h * 32 + c0];
#pragma unroll
      for (int j = 0; j < 8; ++j) d += qrow[h * 32 + c0 + j] * (float)xv[j];
    }
    d *= 0.17677669529663687f;
    float4 g = gx4[s];
    float4 pk = qpks[h];
    d += g.x * pk.x + g.y * pk.y + g.z * pk.z + pk.w;
    if (smask[s]) d = -1e30f;
    sc[h][s] = d;
  }
  __syncthreads();
  if (t < H_) {  // softmax + pgx
    float mx = -3.4e38f;
#pragma unroll
    for (int s = 0; s < S_; ++s) mx = fmaxf(mx, sc[t][s]);
    float e[S_], sum = 0.f;
#pragma unroll
    for (int s = 0; s < S_; ++s) { e[s] = expf(sc[t][s] - mx); sum += e[s]; }
    float inv = 1.f / sum;
    float gxx = 0.f, gyy = 0.f, gzz = 0.f;
#pragma unroll
    for (int s = 0; s < S_; ++s) {
      float p = e[s] * inv;
      pw[t][s] = p;
      float4 g = gx4[s];
      gxx += p * g.x; gyy += p * g.y; gzz += p * g.z;
    }
    pgxs[t] = make_float4(gxx, gyy, gzz, 1.f);
  }
  __syncthreads();
  {  // PV
    int h = t >> 5;
    float a = 0.f;
#pragma unroll
    for (int s = 0; s < S_; ++s) a += pw[h][s] * (float)kvs[s][256 + t];
    float4 pv = Pv[t];
    float4 g = pgxs[h];
    a += g.x * pv.x + g.y * pv.y + g.z * pv.z + pv.w;
    aob[(size_t)bq * C_ + t] = (__bf16)a;
  }
}

// ---------------- LN1: out = LN(xa + xb)*g + b, fp32 + bf16 copies ----------
__global__ __launch_bounds__(256) void k_ln1(const float* __restrict__ xa,
                                             const float* __restrict__ xb,
                                             const float* __restrict__ g,
                                             const float* __restrict__ bb,
                                             float* __restrict__ outf,
                                             __bf16* __restrict__ outb) {
  int wid = (blockIdx.x * 256 + threadIdx.x) >> 6;
  int lane = threadIdx.x & 63;
  float4 va = *(const float4*)(xa + (size_t)wid * C_ + lane * 4);
  float4 vb = *(const float4*)(xb + (size_t)wid * C_ + lane * 4);
  float x0 = va.x + vb.x, x1 = va.y + vb.y, x2 = va.z + vb.z, x3 = va.w + vb.w;
  float s = x0 + x1 + x2 + x3;
#pragma unroll
  for (int off = 32; off >= 1; off >>= 1) s += __shfl_xor(s, off);
  float mean = s * (1.f / C_);
  float d0 = x0 - mean, d1 = x1 - mean, d2 = x2 - mean, d3 = x3 - mean;
  float v = d0 * d0 + d1 * d1 + d2 * d2 + d3 * d3;
#pragma unroll
  for (int off = 32; off >= 1; off >>= 1) v += __shfl_xor(v, off);
  float inv = 1.f / sqrtf(v * (1.f / C_) + EPS_);
  float4 g4 = *(const float4*)(g + lane * 4);
  float4 b4 = *(const float4*)(bb + lane * 4);
  float4 o;
  o.x = d0 * inv * g4.x + b4.x;
  o.y = d1 * inv * g4.y + b4.y;
  o.z = d2 * inv * g4.z + b4.z;
  o.w = d3 * inv * g4.w + b4.w;
  *(float4*)(outf + (size_t)wid * C_ + lane * 4) = o;
  __bf16* ob = outb + (size_t)wid * C_ + lane * 4;
  ob[0] = (__bf16)o.x; ob[1] = (__bf16)o.y; ob[2] = (__bf16)o.z; ob[3] = (__bf16)o.w;
}

// ---- fused ff2-reduce + LN2 + output transpose ------------------------------
// out(B,C,NQ) = LN(x1 + sum_ks ff2p[ks] + lin2_b)^T
__global__ __launch_bounds__(256) void k_lnt(const float* __restrict__ xa,
                                             const __bf16* __restrict__ ff2p,
                                             const float* __restrict__ l2bias,
                                             const float* __restrict__ g,
                                             const float* __restrict__ bb,
                                             float* __restrict__ out) {
  __shared__ float buf[32][257];
  int z = blockIdx.y, nq0 = blockIdx.x * 32;
  int t = threadIdx.x;
  int w = t >> 6, lane = t & 63;
  float4 g4 = *(const float4*)(g + lane * 4);
  float4 b4 = *(const float4*)(bb + lane * 4);
  float4 l2b = *(const float4*)(l2bias + lane * 4);
#pragma unroll
  for (int rr = 0; rr < 8; ++rr) {
    int row = w * 8 + rr;
    size_t grow = (size_t)z * NQ_ + nq0 + row;
    float4 va = *(const float4*)(xa + grow * C_ + lane * 4);
    float x0 = va.x + l2b.x, x1 = va.y + l2b.y, x2 = va.z + l2b.z, x3 = va.w + l2b.w;
#pragma unroll
    for (int ks = 0; ks < KS_; ++ks) {
      bf16x4 p = *(const bf16x4*)&ff2p[((size_t)ks * BQ_ + grow) * C_ + lane * 4];
      x0 += (float)p[0]; x1 += (float)p[1]; x2 += (float)p[2]; x3 += (float)p[3];
    }
    float s = x0 + x1 + x2 + x3;
#pragma unroll
    for (int off = 32; off >= 1; off >>= 1) s += __shfl_xor(s, off);
    float mean = s * (1.f / C_);
    float d0 = x0 - mean, d1 = x1 - mean, d2 = x2 - mean, d3 = x3 - mean;
    float v = d0 * d0 + d1 * d1 + d2 * d2 + d3 * d3;
#pragma unroll
    for (int off = 32; off >= 1; off >>= 1) v += __shfl_xor(v, off);
    float inv = 1.f / sqrtf(v * (1.f / C_) + EPS_);
    buf[row][lane * 4 + 0] = d0 * inv * g4.x + b4.x;
    buf[row][lane * 4 + 1] = d1 * inv * g4.y + b4.y;
    buf[row][lane * 4 + 2] = d2 * inv * g4.z + b4.z;
    buf[row][lane * 4 + 3] = d3 * inv * g4.w + b4.w;
  }
  __syncthreads();
  int tx = t & 31, ty = t >> 5;
#pragma unroll
  for (int ci = 0; ci < 32; ++ci) {
    int c = ci * 8 + ty;
    out[((size_t)z * C_ + c) * NQ_ + nq0 + tx] = buf[tx][c];
  }
}

extern "C" void kernel_launch(void* const* d_in, const int* in_sizes, int n_in,
                              void* d_out, int out_size, void* d_ws, size_t ws_size,
                              hipStream_t stream) {
  const float* query     = (const float*)d_in[0];
  const float* key       = (const float*)d_in[1];
  const float* query_pos = (const float*)d_in[2];
  const float* key_pos   = (const float*)d_in[3];
  const float* q_w = (const float*)d_in[4];  const float* q_b = (const float*)d_in[5];
  const float* k_w = (const float*)d_in[6];  const float* k_b = (const float*)d_in[7];
  const float* v_w = (const float*)d_in[8];  const float* v_b = (const float*)d_in[9];
  const float* o_w = (const float*)d_in[10]; const float* o_b = (const float*)d_in[11];
  const float* lin1_w = (const float*)d_in[12]; const float* lin1_b = (const float*)d_in[13];
  const float* lin2_w = (const float*)d_in[14]; const float* lin2_b = (const float*)d_in[15];
  const float* n1_g = (const float*)d_in[16]; const float* n1_b = (const float*)d_in[17];
  const float* n2_g = (const float*)d_in[18]; const float* n2_b = (const float*)d_in[19];
  const float* qpe_w = (const float*)d_in[20]; const float* qpe_b = (const float*)d_in[21];
  const float* kpe_w = (const float*)d_in[22]; const float* kpe_b = (const float*)d_in[23];
  float* out = (float*)d_out;

  const size_t BQc = (size_t)BQ_ * C_;
  float* w = (float*)d_ws;
  size_t o = 0;
  // ---- workspace carve (~128 MB) ----
  __bf16* keyTb = (__bf16*)(w + o); o += (size_t)B_ * NK_ * C_ / 2;   // 16.8 MB
  float* qtok  = w + o; o += BQc;
  float* x1    = w + o; o += BQc;
  float* attno = w + o; o += BQc;
  __bf16* khvbuf = (__bf16*)(w + o); o += (size_t)B_ * NK_ * 512 / 2; // 33.5 MB; ff1b overlay
  __bf16* ff2p = (__bf16*)(w + o); o += BQc * KS_ / 2;                // 33.5 MB bf16 partials
  __bf16* qinb = (__bf16*)(w + o); o += BQc / 2;
  __bf16* qhb  = (__bf16*)(w + o); o += BQc / 2;
  __bf16* aob  = (__bf16*)(w + o); o += BQc / 2;
  __bf16* x1b  = (__bf16*)(w + o); o += BQc / 2;
  __bf16* qwb  = (__bf16*)(w + o); o += (size_t)C_ * C_ / 2;
  __bf16* kvwb = (__bf16*)(w + o); o += (size_t)C_ * C_;              // (512,256) = k_w ++ v_w
  __bf16* owb  = (__bf16*)(w + o); o += (size_t)C_ * C_ / 2;
  __bf16* l1b  = (__bf16*)(w + o); o += (size_t)C_ * FF_ / 2;
  __bf16* l2b  = (__bf16*)(w + o); o += (size_t)C_ * FF_ / 2;
  float4* Pk   = (float4*)(w + o); o += C_ * 4;
  float4* Pv   = (float4*)(w + o); o += C_ * 4;
  int* idxb  = (int*)(w + o); o += (size_t)BQ_ * S_;
  int* maskb = (int*)(w + o); o += (size_t)BQ_ * S_;
  __bf16* ff1b = khvbuf;    // khv dead after attnf

  // 1. all preprocessing in one launch
  CvtArgs ca;
  ca.src[0] = q_w; ca.dst[0] = qwb;
  ca.src[1] = k_w; ca.dst[1] = kvwb;
  ca.src[2] = v_w; ca.dst[2] = kvwb + (size_t)C_ * C_;
  ca.src[3] = o_w; ca.dst[3] = owb;
  ca.src[4] = lin1_w; ca.dst[4] = l1b;
  ca.src[5] = lin2_w; ca.dst[5] = l2b;
  k_prep<<<NPREP, 256, 0, stream>>>(query, key, query_pos, key_pos,
                                    qpe_w, qpe_b, k_w, k_b, v_w, v_b,
                                    kpe_w, kpe_b, ca,
                                    keyTb, qtok, qinb, Pk, Pv, idxb, maskb);
  // 2. khv = key_feat @ [k_w|v_w]^T  +  qh = qin @ q_w.T + q_b
  k_gemm2<<<1024 + 128, 256, 0, stream>>>(keyTb, kvwb, khvbuf, qinb, qwb, q_b, qhb);
  // 3. fused attention
  k_attnf<<<BQ_, 256, 0, stream>>>(khvbuf, key_pos, query_pos, idxb, maskb,
                                   qhb, Pk, Pv, aob);
  // 4. o projection (fp32 out), BM=128/BN=64 (R6 shape — R7's 64/64 regressed)
  k_gemm<128, 64, 0, 0><<<dim3(C_ / 64, BQ_ / 128), 256, 0, stream>>>(
      aob, owb, o_b, attno, C_, C_);
  // 5. x1 = LN(qtok + attno), fp32 + bf16
  k_ln1<<<BQ_ / 4, 256, 0, stream>>>(qtok, attno, n1_g, n1_b, x1, x1b);
  // 6. ff1(bf16) = relu(x1 @ lin1.T + b)   [overlays khvbuf]
  k_gemm<128, 128, 1, 1><<<dim3(FF_ / 128, BQ_ / 128), 256, 0, stream>>>(
      x1b, l1b, lin1_b, ff1b, FF_, C_);
  // 7. ff2 split-K: 8 chunks of 256 -> bf16 partials (4 K-iters/block, 4 blk/CU)
  k_gemmsk<<<dim3(C_ / 128, BQ_ / 128, KS_), 256, 0, stream>>>(ff1b, l2b, ff2p);
  // 8. out = transpose(LN(x1 + sum(ff2p) + lin2_b))
  k_lnt<<<dim3(NQ_ / 32, B_), 256, 0, stream>>>(x1, ff2p, lin2_b, n2_g, n2_b, out);
}

// Round 9
// 261.125 us; speedup vs baseline: 1.1927x; 1.0486x over previous
//
#include <hip/hip_runtime.h>
#include <cstdint>

#define B_   8
#define C_   256
#define NQ_  1024
#define NK_  4096
#define S_   16
#define H_   8
#define FF_  2048
#define DH_  32
#define BQ_  (B_*NQ_)
#define EPS_ 1e-5f
#define KS_  8     // ff2 split-K factor

typedef __bf16 bf16x8 __attribute__((ext_vector_type(8)));
typedef __bf16 bf16x4 __attribute__((ext_vector_type(4)));
typedef float  f32x4  __attribute__((ext_vector_type(4)));

struct CvtArgs {
  const float* src[6];
  __bf16* dst[6];
};

// ================= k_prep: one launch for all preprocessing =================
// segment order (box query FIRST — latency-bound, overlaps the rest):
//   [0, 2048)        box query (1 wave/query, 4-chunk batched scan)
//   [2048, 10240)    key transpose (B,C,NK)->(B,NK,C) bf16
//   [10240, 12288)   query transpose + qpe -> qtok fp32, qinb bf16
//   [12288, 13568)   weight casts (6 tensors)
//   [13568, 13584)   Pk/Pv folded kpe projections
#define SEGA 2048
#define SEGB 10240
#define SEGC 12288
#define SEGD 13568
#define NPREP 13584

__global__ __launch_bounds__(256) void k_prep(
    const float* __restrict__ query, const float* __restrict__ key,
    const float* __restrict__ query_pos, const float* __restrict__ key_pos,
    const float* __restrict__ qpe_w, const float* __restrict__ qpe_b,
    const float* __restrict__ k_w, const float* __restrict__ k_b,
    const float* __restrict__ v_w, const float* __restrict__ v_b,
    const float* __restrict__ kpe_w, const float* __restrict__ kpe_b,
    CvtArgs ca,
    __bf16* __restrict__ keyTb, float* __restrict__ qtok,
    __bf16* __restrict__ qinb,
    float4* __restrict__ Pk, float4* __restrict__ Pv,
    int* __restrict__ idxo, int* __restrict__ masko) {
  __shared__ __align__(16) float smem[1248];
  int blk = blockIdx.x, t = threadIdx.x;
  int tx = t & 31, ty = t >> 5;

  if (blk < SEGA) {
    // ---- box query: batched 4-chunk scan (independent loads, then ballots) --
    int lane = t & 63;
    int q = blk * 4 + (t >> 6);
    int b = q >> 10;
    const float* kpb = key_pos + (size_t)b * NK_ * 3;
    const float* qp = query_pos + (size_t)q * 6;
    float cx = qp[0], cy = qp[1], cz = qp[2];
    float hx = 0.5f * qp[3], hy = 0.5f * qp[4], hz = 0.5f * qp[5];
    int* iq = idxo + (size_t)q * S_;
    int found = 0;
    for (int ch = 0; ch < NK_ / 64; ch += 4) {
      float dx[4], dy[4], dz[4];
#pragma unroll
      for (int u = 0; u < 4; ++u) {
        int k = (ch + u) * 64 + lane;
        dx[u] = fabsf(kpb[k * 3 + 0] - cx);
        dy[u] = fabsf(kpb[k * 3 + 1] - cy);
        dz[u] = fabsf(kpb[k * 3 + 2] - cz);
      }
#pragma unroll
      for (int u = 0; u < 4; ++u) {
        bool inside = (dx[u] <= hx) && (dy[u] <= hy) && (dz[u] <= hz);
        unsigned long long bal = __ballot(inside);
        if (inside) {
          int slot = found + __popcll(bal & ((1ull << lane) - 1ull));
          if (slot < S_) iq[slot] = (ch + u) * 64 + lane;
        }
        found += __popcll(bal);
      }
      if (found >= S_) break;
    }
    if (found > S_) found = S_;
    if (lane < S_) {
      int m = (lane < found) ? 0 : 1;
      if (lane >= found) iq[lane] = 0;
      if (lane == 0) m = 0;
      masko[(size_t)q * S_ + lane] = m;
    }
  } else if (blk < SEGB) {
    // ---- key transpose: (z, C, NK) -> (z, NK, C) bf16 ----
    int local = blk - SEGA;
    float (*tt)[33] = (float(*)[33])smem;
    int x = local & 127, y = (local >> 7) & 7, z = local >> 10;
    int j0 = x * 32, i0 = y * 32;
    const float* inz = key + (size_t)z * C_ * NK_;
    __bf16* outz = keyTb + (size_t)z * NK_ * C_;
#pragma unroll
    for (int r = 0; r < 32; r += 8)
      tt[ty + r][tx] = inz[(size_t)(i0 + ty + r) * NK_ + (j0 + tx)];
    __syncthreads();
#pragma unroll
    for (int r = 0; r < 32; r += 8)
      outz[(size_t)(j0 + ty + r) * C_ + (i0 + tx)] = (__bf16)tt[tx][ty + r];
  } else if (blk < SEGC) {
    // ---- query transpose + qpe ----
    int local = blk - SEGB;
    float (*tt)[33] = (float(*)[33])smem;
    float (*sqp)[6] = (float(*)[6])(smem + 1056);
    int x = local & 31, y = (local >> 5) & 7, z = local >> 8;
    int nq0 = x * 32, c0 = y * 32;
    const float* inz = query + (size_t)z * C_ * NQ_;
#pragma unroll
    for (int r = 0; r < 32; r += 8)
      tt[ty + r][tx] = inz[(size_t)(c0 + ty + r) * NQ_ + (nq0 + tx)];
    if (t < 192)
      sqp[t / 6][t % 6] = query_pos[((size_t)z * NQ_ + nq0 + t / 6) * 6 + (t % 6)];
    int c = c0 + tx;
    float w0 = qpe_w[c * 6 + 0], w1 = qpe_w[c * 6 + 1], w2 = qpe_w[c * 6 + 2];
    float w3 = qpe_w[c * 6 + 3], w4 = qpe_w[c * 6 + 4], w5 = qpe_w[c * 6 + 5];
    float wb = qpe_b[c];
    __syncthreads();
#pragma unroll
    for (int r = 0; r < 32; r += 8) {
      int nql = ty + r;
      size_t row = (size_t)z * NQ_ + nq0 + nql;
      float v = tt[tx][nql];
      float pe = wb + sqp[nql][0] * w0 + sqp[nql][1] * w1 + sqp[nql][2] * w2 +
                 sqp[nql][3] * w3 + sqp[nql][4] * w4 + sqp[nql][5] * w5;
      qtok[row * C_ + c] = v;
      qinb[row * C_ + c] = (__bf16)(v + pe);
    }
  } else if (blk < SEGD) {
    // ---- weight casts ----
    int local = blk - SEGC;
    int idx, base;
    if (local < 64)       { idx = 0; base = local; }
    else if (local < 128) { idx = 1; base = local - 64; }
    else if (local < 192) { idx = 2; base = local - 128; }
    else if (local < 256) { idx = 3; base = local - 192; }
    else if (local < 768) { idx = 4; base = local - 256; }
    else                  { idx = 5; base = local - 768; }
    size_t off = (size_t)base * 1024 + t * 4;
    float4 v = *(const float4*)(ca.src[idx] + off);
    __bf16* o = ca.dst[idx] + off;
    o[0] = (__bf16)v.x; o[1] = (__bf16)v.y; o[2] = (__bf16)v.z; o[3] = (__bf16)v.w;
  } else {
    // ---- Pk / Pv fold ----
    int local = blk - SEGD;
    int bx = local & 7, bv = local >> 3;
    const float* w  = bv ? v_w : k_w;
    const float* wb = bv ? v_b : k_b;
    float4* P = bv ? Pv : Pk;
    float4 (*red)[8] = (float4(*)[8])smem;
    int nl = t >> 3, ks = (t & 7) * 32;
    int n = bx * 32 + nl;
    const float* wr = w + (size_t)n * C_;
    float p0 = 0.f, p1 = 0.f, p2 = 0.f, pb = 0.f;
#pragma unroll
    for (int k = ks; k < ks + 32; ++k) {
      float wv = wr[k];
      p0 += kpe_w[k * 3 + 0] * wv;
      p1 += kpe_w[k * 3 + 1] * wv;
      p2 += kpe_w[k * 3 + 2] * wv;
      pb += kpe_b[k] * wv;
    }
    red[nl][t & 7] = make_float4(p0, p1, p2, pb);
    __syncthreads();
    if (t < 32) {
      float4 s = red[t][0];
#pragma unroll
      for (int j = 1; j < 8; ++j) {
        float4 r = red[t][j];
        s.x += r.x; s.y += r.y; s.z += r.z; s.w += r.w;
      }
      s.w += wb[bx * 32 + t];
      P[bx * 32 + t] = s;
    }
  }
}

// ============== generalized bf16 MFMA GEMM body (k-range) ==============
template <int BM, int BN, int RELU, int OUT_BF16>
__device__ __forceinline__ void gemm_body(
    const __bf16* __restrict__ A, const __bf16* __restrict__ Wn,
    const float* __restrict__ bias, void* __restrict__ outp,
    int n0, int m0, int N, int K, int kbeg, int kend) {
  constexpr int MI = BM / 32, JN = BN / 32;
  constexpr int AIT = (BM * 64) / 2048, BIT = (BN * 64) / 2048;
  __shared__ __bf16 As[BM][72];
  __shared__ __bf16 Bs[BN][72];
  int t = threadIdx.x;
  int lane = t & 63, w = t >> 6;
  int lane16 = lane & 15, quad = lane >> 4;
  int wm = (w & 1) * (BM / 2), wn = (w >> 1) * (BN / 2);

  f32x4 acc[MI][JN];
#pragma unroll
  for (int i = 0; i < MI; ++i)
#pragma unroll
    for (int j = 0; j < JN; ++j) acc[i][j] = (f32x4){0.f, 0.f, 0.f, 0.f};

  for (int k0 = kbeg; k0 < kend; k0 += 64) {
#pragma unroll
    for (int i = 0; i < AIT; ++i) {
      int ii = i * 256 + t;
      int m = ii >> 3, kc = (ii & 7) * 8;
      *(bf16x8*)&As[m][kc] = *(const bf16x8*)&A[(size_t)(m0 + m) * K + k0 + kc];
    }
#pragma unroll
    for (int i = 0; i < BIT; ++i) {
      int ii = i * 256 + t;
      int m = ii >> 3, kc = (ii & 7) * 8;
      *(bf16x8*)&Bs[m][kc] = *(const bf16x8*)&Wn[(size_t)(n0 + m) * K + k0 + kc];
    }
    __syncthreads();
#pragma unroll
    for (int kk = 0; kk < 64; kk += 32) {
      bf16x8 af[MI], bfr[JN];
#pragma unroll
      for (int i = 0; i < MI; ++i)
        af[i] = *(const bf16x8*)&As[wm + i * 16 + lane16][kk + quad * 8];
#pragma unroll
      for (int j = 0; j < JN; ++j)
        bfr[j] = *(const bf16x8*)&Bs[wn + j * 16 + lane16][kk + quad * 8];
#pragma unroll
      for (int i = 0; i < MI; ++i)
#pragma unroll
        for (int j = 0; j < JN; ++j)
          acc[i][j] = __builtin_amdgcn_mfma_f32_16x16x32_bf16(af[i], bfr[j], acc[i][j], 0, 0, 0);
    }
    __syncthreads();
  }

#pragma unroll
  for (int j = 0; j < JN; ++j) {
    int col = n0 + wn + j * 16 + lane16;
    float bv = bias ? bias[col] : 0.f;
#pragma unroll
    for (int i = 0; i < MI; ++i) {
#pragma unroll
      for (int r = 0; r < 4; ++r) {
        int row = m0 + wm + i * 16 + quad * 4 + r;
        float v = acc[i][j][r] + bv;
        if (RELU) v = fmaxf(v, 0.f);
        if (OUT_BF16)
          ((__bf16*)outp)[(size_t)row * N + col] = (__bf16)v;
        else
          ((float*)outp)[(size_t)row * N + col] = v;
      }
    }
  }
}

template <int BM, int BN, int RELU, int OUT_BF16>
__global__ __launch_bounds__(256) void k_gemm(
    const __bf16* __restrict__ A, const __bf16* __restrict__ Wn,
    const float* __restrict__ bias, void* __restrict__ outp, int N, int K) {
  gemm_body<BM, BN, RELU, OUT_BF16>(A, Wn, bias, outp,
                                    blockIdx.x * BN, blockIdx.y * BM, N, K, 0, K);
}

// ---- split-K ff2: partials[ks][BQ][C] bf16 (bias added in k_lnt) ----
__global__ __launch_bounds__(256) void k_gemmsk(
    const __bf16* __restrict__ A, const __bf16* __restrict__ Wn,
    __bf16* __restrict__ partials) {
  int ks = blockIdx.z;
  int kbeg = ks * (FF_ / KS_), kend = kbeg + FF_ / KS_;
  gemm_body<128, 128, 0, 1>(A, Wn, nullptr,
                            partials + (size_t)ks * BQ_ * C_,
                            blockIdx.x * 128, blockIdx.y * 128, C_, FF_, kbeg, kend);
}

// ---- split-K o-proj: 2 partials (bias added in k_ln1) ----
__global__ __launch_bounds__(256) void k_gemmsko(
    const __bf16* __restrict__ A, const __bf16* __restrict__ Wn,
    __bf16* __restrict__ partials) {
  int ks = blockIdx.z;
  int kbeg = ks * 128, kend = kbeg + 128;
  gemm_body<128, 64, 0, 1>(A, Wn, nullptr,
                           partials + (size_t)ks * BQ_ * C_,
                           blockIdx.x * 64, blockIdx.y * 128, C_, C_, kbeg, kend);
}

// ---- merged khv GEMM (1024 blocks) + qh GEMM (128 blocks) ----
__global__ __launch_bounds__(256) void k_gemm2(
    const __bf16* __restrict__ keyTb, const __bf16* __restrict__ kvwb,
    __bf16* __restrict__ khvbuf,
    const __bf16* __restrict__ qinb, const __bf16* __restrict__ qwb,
    const float* __restrict__ q_b, __bf16* __restrict__ qhb) {
  int blk = blockIdx.x;
  const __bf16 *A, *Wn; const float* bias; __bf16* outp; int n0, m0, N;
  if (blk < 1024) {
    A = keyTb; Wn = kvwb; bias = nullptr; outp = khvbuf;
    n0 = (blk & 3) * 128; m0 = (blk >> 2) * 128; N = 512;
  } else {
    int l = blk - 1024;
    A = qinb; Wn = qwb; bias = q_b; outp = qhb;
    n0 = (l & 1) * 128; m0 = (l >> 1) * 128; N = 256;
  }
  gemm_body<128, 128, 0, 1>(A, Wn, bias, outp, n0, m0, N, 256, 0, 256);
}

// ---- fused attention (unchanged from R8) ----
__global__ __launch_bounds__(256) void k_attnf(
    const __bf16* __restrict__ khv,
    const float* __restrict__ key_pos,
    const float* __restrict__ query_pos,
    const int* __restrict__ idx,
    const int* __restrict__ maskb,
    const __bf16* __restrict__ qhb,
    const float4* __restrict__ Pk,
    const float4* __restrict__ Pv,
    __bf16* __restrict__ aob) {
  __shared__ __bf16 kvs[S_][520];
  __shared__ float qrow[C_];
  __shared__ float sc[H_][S_];
  __shared__ float pw[H_][S_];
  __shared__ float4 gx4[S_];
  __shared__ float4 pgxs[H_];
  __shared__ float4 qpks[H_];
  __shared__ int srow[S_], smask[S_];
  int bq = blockIdx.x, b = bq >> 10, t = threadIdx.x;

  if (t < S_) {
    int k = idx[(size_t)bq * S_ + t];
    srow[t] = b * NK_ + k;
    smask[t] = maskb[(size_t)bq * S_ + t];
    const float* kpp = key_pos + ((size_t)b * NK_ + k) * 3;
    const float* qp  = query_pos + (size_t)bq * 6;
    gx4[t] = make_float4(kpp[0] - qp[0], kpp[1] - qp[1], kpp[2] - qp[2], 1.f);
  }
  float qv_t = (float)qhb[(size_t)bq * C_ + t];
  qrow[t] = qv_t;
  {
    float4 p = Pk[t];
    p.x *= qv_t; p.y *= qv_t; p.z *= qv_t; p.w *= qv_t;
#pragma unroll
    for (int off = 16; off >= 1; off >>= 1) {
      p.x += __shfl_xor(p.x, off);
      p.y += __shfl_xor(p.y, off);
      p.z += __shfl_xor(p.z, off);
      p.w += __shfl_xor(p.w, off);
    }
    if ((t & 31) == 0) {
      const float s = 0.17677669529663687f;
      qpks[t >> 5] = make_float4(p.x * s, p.y * s, p.z * s, p.w * s);
    }
  }
  __syncthreads();
  {
    int s = t >> 4, c0 = (t & 15) * 32;
    const __bf16* src = khv + (size_t)srow[s] * 512 + c0;
    *(bf16x8*)&kvs[s][c0]      = *(const bf16x8*)&src[0];
    *(bf16x8*)&kvs[s][c0 + 8]  = *(const bf16x8*)&src[8];
    *(bf16x8*)&kvs[s][c0 + 16] = *(const bf16x8*)&src[16];
    *(bf16x8*)&kvs[s][c0 + 24] = *(const bf16x8*)&src[24];
  }
  __syncthreads();
  if (t < H_ * S_) {
    int h = t >> 4, s = t & (S_ - 1);
    float d = 0.f;
#pragma unroll
    for (int c0 = 0; c0 < 32; c0 += 8) {
      bf16x8 xv = *(const bf16x8*)&kvs[s][h * 32 + c0];
#pragma unroll
      for (int j = 0; j < 8; ++j) d += qrow[h * 32 + c0 + j] * (float)xv[j];
    }
    d *= 0.17677669529663687f;
    float4 g = gx4[s];
    float4 pk = qpks[h];
    d += g.x * pk.x + g.y * pk.y + g.z * pk.z + pk.w;
    if (smask[s]) d = -1e30f;
    sc[h][s] = d;
  }
  __syncthreads();
  if (t < H_) {
    float mx = -3.4e38f;
#pragma unroll
    for (int s = 0; s < S_; ++s) mx = fmaxf(mx, sc[t][s]);
    float e[S_], sum = 0.f;
#pragma unroll
    for (int s = 0; s < S_; ++s) { e[s] = expf(sc[t][s] - mx); sum += e[s]; }
    float inv = 1.f / sum;
    float gxx = 0.f, gyy = 0.f, gzz = 0.f;
#pragma unroll
    for (int s = 0; s < S_; ++s) {
      float p = e[s] * inv;
      pw[t][s] = p;
      float4 g = gx4[s];
      gxx += p * g.x; gyy += p * g.y; gzz += p * g.z;
    }
    pgxs[t] = make_float4(gxx, gyy, gzz, 1.f);
  }
  __syncthreads();
  {
    int h = t >> 5;
    float a = 0.f;
#pragma unroll
    for (int s = 0; s < S_; ++s) a += pw[h][s] * (float)kvs[s][256 + t];
    float4 pv = Pv[t];
    float4 g = pgxs[h];
    a += g.x * pv.x + g.y * pv.y + g.z * pv.z + pv.w;
    aob[(size_t)bq * C_ + t] = (__bf16)a;
  }
}

// ---- LN1: x1 = LN(qtok + op2[0]+op2[1] + o_b)*g + b, fp32 + bf16 copies ----
__global__ __launch_bounds__(256) void k_ln1(const float* __restrict__ xa,
                                             const __bf16* __restrict__ op2,
                                             const float* __restrict__ obias,
                                             const float* __restrict__ g,
                                             const float* __restrict__ bb,
                                             float* __restrict__ outf,
                                             __bf16* __restrict__ outb) {
  int wid = (blockIdx.x * 256 + threadIdx.x) >> 6;
  int lane = threadIdx.x & 63;
  float4 va = *(const float4*)(xa + (size_t)wid * C_ + lane * 4);
  float4 ob4 = *(const float4*)(obias + lane * 4);
  bf16x4 p0 = *(const bf16x4*)&op2[(size_t)wid * C_ + lane * 4];
  bf16x4 p1 = *(const bf16x4*)&op2[(size_t)BQ_ * C_ + (size_t)wid * C_ + lane * 4];
  float x0 = va.x + ob4.x + (float)p0[0] + (float)p1[0];
  float x1 = va.y + ob4.y + (float)p0[1] + (float)p1[1];
  float x2 = va.z + ob4.z + (float)p0[2] + (float)p1[2];
  float x3 = va.w + ob4.w + (float)p0[3] + (float)p1[3];
  float s = x0 + x1 + x2 + x3;
#pragma unroll
  for (int off = 32; off >= 1; off >>= 1) s += __shfl_xor(s, off);
  float mean = s * (1.f / C_);
  float d0 = x0 - mean, d1 = x1 - mean, d2 = x2 - mean, d3 = x3 - mean;
  float v = d0 * d0 + d1 * d1 + d2 * d2 + d3 * d3;
#pragma unroll
  for (int off = 32; off >= 1; off >>= 1) v += __shfl_xor(v, off);
  float inv = 1.f / sqrtf(v * (1.f / C_) + EPS_);
  float4 g4 = *(const float4*)(g + lane * 4);
  float4 b4 = *(const float4*)(bb + lane * 4);
  float4 o;
  o.x = d0 * inv * g4.x + b4.x;
  o.y = d1 * inv * g4.y + b4.y;
  o.z = d2 * inv * g4.z + b4.z;
  o.w = d3 * inv * g4.w + b4.w;
  *(float4*)(outf + (size_t)wid * C_ + lane * 4) = o;
  __bf16* obp = outb + (size_t)wid * C_ + lane * 4;
  obp[0] = (__bf16)o.x; obp[1] = (__bf16)o.y; obp[2] = (__bf16)o.z; obp[3] = (__bf16)o.w;
}

// ---- fused ff2-reduce + LN2 + output transpose ------------------------------
__global__ __launch_bounds__(256) void k_lnt(const float* __restrict__ xa,
                                             const __bf16* __restrict__ ff2p,
                                             const float* __restrict__ l2bias,
                                             const float* __restrict__ g,
                                             const float* __restrict__ bb,
                                             float* __restrict__ out) {
  __shared__ float buf[32][257];
  int z = blockIdx.y, nq0 = blockIdx.x * 32;
  int t = threadIdx.x;
  int w = t >> 6, lane = t & 63;
  float4 g4 = *(const float4*)(g + lane * 4);
  float4 b4 = *(const float4*)(bb + lane * 4);
  float4 l2b = *(const float4*)(l2bias + lane * 4);
#pragma unroll
  for (int rr = 0; rr < 8; ++rr) {
    int row = w * 8 + rr;
    size_t grow = (size_t)z * NQ_ + nq0 + row;
    float4 va = *(const float4*)(xa + grow * C_ + lane * 4);
    float x0 = va.x + l2b.x, x1 = va.y + l2b.y, x2 = va.z + l2b.z, x3 = va.w + l2b.w;
#pragma unroll
    for (int ks = 0; ks < KS_; ++ks) {
      bf16x4 p = *(const bf16x4*)&ff2p[((size_t)ks * BQ_ + grow) * C_ + lane * 4];
      x0 += (float)p[0]; x1 += (float)p[1]; x2 += (float)p[2]; x3 += (float)p[3];
    }
    float s = x0 + x1 + x2 + x3;
#pragma unroll
    for (int off = 32; off >= 1; off >>= 1) s += __shfl_xor(s, off);
    float mean = s * (1.f / C_);
    float d0 = x0 - mean, d1 = x1 - mean, d2 = x2 - mean, d3 = x3 - mean;
    float v = d0 * d0 + d1 * d1 + d2 * d2 + d3 * d3;
#pragma unroll
    for (int off = 32; off >= 1; off >>= 1) v += __shfl_xor(v, off);
    float inv = 1.f / sqrtf(v * (1.f / C_) + EPS_);
    buf[row][lane * 4 + 0] = d0 * inv * g4.x + b4.x;
    buf[row][lane * 4 + 1] = d1 * inv * g4.y + b4.y;
    buf[row][lane * 4 + 2] = d2 * inv * g4.z + b4.z;
    buf[row][lane * 4 + 3] = d3 * inv * g4.w + b4.w;
  }
  __syncthreads();
  int tx = t & 31, ty = t >> 5;
#pragma unroll
  for (int ci = 0; ci < 32; ++ci) {
    int c = ci * 8 + ty;
    out[((size_t)z * C_ + c) * NQ_ + nq0 + tx] = buf[tx][c];
  }
}

extern "C" void kernel_launch(void* const* d_in, const int* in_sizes, int n_in,
                              void* d_out, int out_size, void* d_ws, size_t ws_size,
                              hipStream_t stream) {
  const float* query     = (const float*)d_in[0];
  const float* key       = (const float*)d_in[1];
  const float* query_pos = (const float*)d_in[2];
  const float* key_pos   = (const float*)d_in[3];
  const float* q_w = (const float*)d_in[4];  const float* q_b = (const float*)d_in[5];
  const float* k_w = (const float*)d_in[6];  const float* k_b = (const float*)d_in[7];
  const float* v_w = (const float*)d_in[8];  const float* v_b = (const float*)d_in[9];
  const float* o_w = (const float*)d_in[10]; const float* o_b = (const float*)d_in[11];
  const float* lin1_w = (const float*)d_in[12]; const float* lin1_b = (const float*)d_in[13];
  const float* lin2_w = (const float*)d_in[14]; const float* lin2_b = (const float*)d_in[15];
  const float* n1_g = (const float*)d_in[16]; const float* n1_b = (const float*)d_in[17];
  const float* n2_g = (const float*)d_in[18]; const float* n2_b = (const float*)d_in[19];
  const float* qpe_w = (const float*)d_in[20]; const float* qpe_b = (const float*)d_in[21];
  const float* kpe_w = (const float*)d_in[22]; const float* kpe_b = (const float*)d_in[23];
  float* out = (float*)d_out;

  const size_t BQc = (size_t)BQ_ * C_;
  float* w = (float*)d_ws;
  size_t o = 0;
  // ---- workspace carve (~128 MB) ----
  __bf16* keyTb = (__bf16*)(w + o); o += (size_t)B_ * NK_ * C_ / 2;   // 16.8 MB
  float* qtok  = w + o; o += BQc;
  float* x1    = w + o; o += BQc;
  __bf16* op2  = (__bf16*)(w + o); o += BQc;                          // 2 o-proj partials
  __bf16* khvbuf = (__bf16*)(w + o); o += (size_t)B_ * NK_ * 512 / 2; // 33.5 MB; ff1b overlay
  __bf16* ff2p = (__bf16*)(w + o); o += BQc * KS_ / 2;                // 33.5 MB
  __bf16* qinb = (__bf16*)(w + o); o += BQc / 2;
  __bf16* qhb  = (__bf16*)(w + o); o += BQc / 2;
  __bf16* aob  = (__bf16*)(w + o); o += BQc / 2;
  __bf16* x1b  = (__bf16*)(w + o); o += BQc / 2;
  __bf16* qwb  = (__bf16*)(w + o); o += (size_t)C_ * C_ / 2;
  __bf16* kvwb = (__bf16*)(w + o); o += (size_t)C_ * C_;              // (512,256) = k_w ++ v_w
  __bf16* owb  = (__bf16*)(w + o); o += (size_t)C_ * C_ / 2;
  __bf16* l1b  = (__bf16*)(w + o); o += (size_t)C_ * FF_ / 2;
  __bf16* l2b  = (__bf16*)(w + o); o += (size_t)C_ * FF_ / 2;
  float4* Pk   = (float4*)(w + o); o += C_ * 4;
  float4* Pv   = (float4*)(w + o); o += C_ * 4;
  int* idxb  = (int*)(w + o); o += (size_t)BQ_ * S_;
  int* maskb = (int*)(w + o); o += (size_t)BQ_ * S_;
  __bf16* ff1b = khvbuf;    // khv dead after attnf

  // 1. all preprocessing in one launch (box query first — latency-bound)
  CvtArgs ca;
  ca.src[0] = q_w; ca.dst[0] = qwb;
  ca.src[1] = k_w; ca.dst[1] = kvwb;
  ca.src[2] = v_w; ca.dst[2] = kvwb + (size_t)C_ * C_;
  ca.src[3] = o_w; ca.dst[3] = owb;
  ca.src[4] = lin1_w; ca.dst[4] = l1b;
  ca.src[5] = lin2_w; ca.dst[5] = l2b;
  k_prep<<<NPREP, 256, 0, stream>>>(query, key, query_pos, key_pos,
                                    qpe_w, qpe_b, k_w, k_b, v_w, v_b,
                                    kpe_w, kpe_b, ca,
                                    keyTb, qtok, qinb, Pk, Pv, idxb, maskb);
  // 2. khv = key_feat @ [k_w|v_w]^T  +  qh = qin @ q_w.T + q_b
  k_gemm2<<<1024 + 128, 256, 0, stream>>>(keyTb, kvwb, khvbuf, qinb, qwb, q_b, qhb);
  // 3. fused attention
  k_attnf<<<BQ_, 256, 0, stream>>>(khvbuf, key_pos, query_pos, idxb, maskb,
                                   qhb, Pk, Pv, aob);
  // 4. o projection split-K=2 -> bf16 partials (512 blocks, 2 K-iters each)
  k_gemmsko<<<dim3(C_ / 64, BQ_ / 128, 2), 256, 0, stream>>>(aob, owb, op2);
  // 5. x1 = LN(qtok + sum(op2) + o_b), fp32 + bf16
  k_ln1<<<BQ_ / 4, 256, 0, stream>>>(qtok, op2, o_b, n1_g, n1_b, x1, x1b);
  // 6. ff1(bf16) = relu(x1 @ lin1.T + b)   [overlays khvbuf]
  k_gemm<128, 128, 1, 1><<<dim3(FF_ / 128, BQ_ / 128), 256, 0, stream>>>(
      x1b, l1b, lin1_b, ff1b, FF_, C_);
  // 7. ff2 split-K: 8 chunks -> bf16 partials
  k_gemmsk<<<dim3(C_ / 128, BQ_ / 128, KS_), 256, 0, stream>>>(ff1b, l2b, ff2p);
  // 8. out = transpose(LN(x1 + sum(ff2p) + lin2_b))
  k_lnt<<<dim3(NQ_ / 32, B_), 256, 0, stream>>>(x1, ff2p, lin2_b, n2_g, n2_b, out);
}

// Round 10
// 258.593 us; speedup vs baseline: 1.2044x; 1.0098x over previous
//
#include <hip/hip_runtime.h>
#include <cstdint>

#define B_   8
#define C_   256
#define NQ_  1024
#define NK_  4096
#define S_   16
#define H_   8
#define FF_  2048
#define DH_  32
#define BQ_  (B_*NQ_)
#define EPS_ 1e-5f
#define KS_  8     // ff2 split-K factor

typedef __bf16 bf16x8 __attribute__((ext_vector_type(8)));
typedef __bf16 bf16x4 __attribute__((ext_vector_type(4)));
typedef float  f32x4  __attribute__((ext_vector_type(4)));

struct CvtArgs {
  const float* src[6];
  __bf16* dst[6];
};

// ================= k_prep: one launch for all preprocessing =================
// segment order (box query FIRST — latency-bound, overlaps the rest):
//   [0, 2048)        box query (1 wave/query, 4-chunk batched scan)
//   [2048, 10240)    key transpose (B,C,NK)->(B,NK,C) bf16
//   [10240, 12288)   query transpose + qpe -> qtok bf16, qinb bf16
//   [12288, 13568)   weight casts (6 tensors)
//   [13568, 13584)   Pk/Pv folded kpe projections
#define SEGA 2048
#define SEGB 10240
#define SEGC 12288
#define SEGD 13568
#define NPREP 13584

__global__ __launch_bounds__(256) void k_prep(
    const float* __restrict__ query, const float* __restrict__ key,
    const float* __restrict__ query_pos, const float* __restrict__ key_pos,
    const float* __restrict__ qpe_w, const float* __restrict__ qpe_b,
    const float* __restrict__ k_w, const float* __restrict__ k_b,
    const float* __restrict__ v_w, const float* __restrict__ v_b,
    const float* __restrict__ kpe_w, const float* __restrict__ kpe_b,
    CvtArgs ca,
    __bf16* __restrict__ keyTb, __bf16* __restrict__ qtokb,
    __bf16* __restrict__ qinb,
    float4* __restrict__ Pk, float4* __restrict__ Pv,
    int* __restrict__ idxo, int* __restrict__ masko) {
  __shared__ __align__(16) float smem[1248];
  int blk = blockIdx.x, t = threadIdx.x;
  int tx = t & 31, ty = t >> 5;

  if (blk < SEGA) {
    // ---- box query: batched 4-chunk scan ----
    int lane = t & 63;
    int q = blk * 4 + (t >> 6);
    int b = q >> 10;
    const float* kpb = key_pos + (size_t)b * NK_ * 3;
    const float* qp = query_pos + (size_t)q * 6;
    float cx = qp[0], cy = qp[1], cz = qp[2];
    float hx = 0.5f * qp[3], hy = 0.5f * qp[4], hz = 0.5f * qp[5];
    int* iq = idxo + (size_t)q * S_;
    int found = 0;
    for (int ch = 0; ch < NK_ / 64; ch += 4) {
      float dx[4], dy[4], dz[4];
#pragma unroll
      for (int u = 0; u < 4; ++u) {
        int k = (ch + u) * 64 + lane;
        dx[u] = fabsf(kpb[k * 3 + 0] - cx);
        dy[u] = fabsf(kpb[k * 3 + 1] - cy);
        dz[u] = fabsf(kpb[k * 3 + 2] - cz);
      }
#pragma unroll
      for (int u = 0; u < 4; ++u) {
        bool inside = (dx[u] <= hx) && (dy[u] <= hy) && (dz[u] <= hz);
        unsigned long long bal = __ballot(inside);
        if (inside) {
          int slot = found + __popcll(bal & ((1ull << lane) - 1ull));
          if (slot < S_) iq[slot] = (ch + u) * 64 + lane;
        }
        found += __popcll(bal);
      }
      if (found >= S_) break;
    }
    if (found > S_) found = S_;
    if (lane < S_) {
      int m = (lane < found) ? 0 : 1;
      if (lane >= found) iq[lane] = 0;
      if (lane == 0) m = 0;
      masko[(size_t)q * S_ + lane] = m;
    }
  } else if (blk < SEGB) {
    // ---- key transpose ----
    int local = blk - SEGA;
    float (*tt)[33] = (float(*)[33])smem;
    int x = local & 127, y = (local >> 7) & 7, z = local >> 10;
    int j0 = x * 32, i0 = y * 32;
    const float* inz = key + (size_t)z * C_ * NK_;
    __bf16* outz = keyTb + (size_t)z * NK_ * C_;
#pragma unroll
    for (int r = 0; r < 32; r += 8)
      tt[ty + r][tx] = inz[(size_t)(i0 + ty + r) * NK_ + (j0 + tx)];
    __syncthreads();
#pragma unroll
    for (int r = 0; r < 32; r += 8)
      outz[(size_t)(j0 + ty + r) * C_ + (i0 + tx)] = (__bf16)tt[tx][ty + r];
  } else if (blk < SEGC) {
    // ---- query transpose + qpe (both outputs bf16) ----
    int local = blk - SEGB;
    float (*tt)[33] = (float(*)[33])smem;
    float (*sqp)[6] = (float(*)[6])(smem + 1056);
    int x = local & 31, y = (local >> 5) & 7, z = local >> 8;
    int nq0 = x * 32, c0 = y * 32;
    const float* inz = query + (size_t)z * C_ * NQ_;
#pragma unroll
    for (int r = 0; r < 32; r += 8)
      tt[ty + r][tx] = inz[(size_t)(c0 + ty + r) * NQ_ + (nq0 + tx)];
    if (t < 192)
      sqp[t / 6][t % 6] = query_pos[((size_t)z * NQ_ + nq0 + t / 6) * 6 + (t % 6)];
    int c = c0 + tx;
    float w0 = qpe_w[c * 6 + 0], w1 = qpe_w[c * 6 + 1], w2 = qpe_w[c * 6 + 2];
    float w3 = qpe_w[c * 6 + 3], w4 = qpe_w[c * 6 + 4], w5 = qpe_w[c * 6 + 5];
    float wb = qpe_b[c];
    __syncthreads();
#pragma unroll
    for (int r = 0; r < 32; r += 8) {
      int nql = ty + r;
      size_t row = (size_t)z * NQ_ + nq0 + nql;
      float v = tt[tx][nql];
      float pe = wb + sqp[nql][0] * w0 + sqp[nql][1] * w1 + sqp[nql][2] * w2 +
                 sqp[nql][3] * w3 + sqp[nql][4] * w4 + sqp[nql][5] * w5;
      qtokb[row * C_ + c] = (__bf16)v;
      qinb[row * C_ + c] = (__bf16)(v + pe);
    }
  } else if (blk < SEGD) {
    // ---- weight casts ----
    int local = blk - SEGC;
    int idx, base;
    if (local < 64)       { idx = 0; base = local; }
    else if (local < 128) { idx = 1; base = local - 64; }
    else if (local < 192) { idx = 2; base = local - 128; }
    else if (local < 256) { idx = 3; base = local - 192; }
    else if (local < 768) { idx = 4; base = local - 256; }
    else                  { idx = 5; base = local - 768; }
    size_t off = (size_t)base * 1024 + t * 4;
    float4 v = *(const float4*)(ca.src[idx] + off);
    __bf16* o = ca.dst[idx] + off;
    o[0] = (__bf16)v.x; o[1] = (__bf16)v.y; o[2] = (__bf16)v.z; o[3] = (__bf16)v.w;
  } else {
    // ---- Pk / Pv fold ----
    int local = blk - SEGD;
    int bx = local & 7, bv = local >> 3;
    const float* w  = bv ? v_w : k_w;
    const float* wb = bv ? v_b : k_b;
    float4* P = bv ? Pv : Pk;
    float4 (*red)[8] = (float4(*)[8])smem;
    int nl = t >> 3, ks = (t & 7) * 32;
    int n = bx * 32 + nl;
    const float* wr = w + (size_t)n * C_;
    float p0 = 0.f, p1 = 0.f, p2 = 0.f, pb = 0.f;
#pragma unroll
    for (int k = ks; k < ks + 32; ++k) {
      float wv = wr[k];
      p0 += kpe_w[k * 3 + 0] * wv;
      p1 += kpe_w[k * 3 + 1] * wv;
      p2 += kpe_w[k * 3 + 2] * wv;
      pb += kpe_b[k] * wv;
    }
    red[nl][t & 7] = make_float4(p0, p1, p2, pb);
    __syncthreads();
    if (t < 32) {
      float4 s = red[t][0];
#pragma unroll
      for (int j = 1; j < 8; ++j) {
        float4 r = red[t][j];
        s.x += r.x; s.y += r.y; s.z += r.z; s.w += r.w;
      }
      s.w += wb[bx * 32 + t];
      P[bx * 32 + t] = s;
    }
  }
}

// ============== generalized bf16 MFMA GEMM body (k-range) ==============
template <int BM, int BN, int RELU, int OUT_BF16>
__device__ __forceinline__ void gemm_body(
    const __bf16* __restrict__ A, const __bf16* __restrict__ Wn,
    const float* __restrict__ bias, void* __restrict__ outp,
    int n0, int m0, int N, int K, int kbeg, int kend) {
  constexpr int MI = BM / 32, JN = BN / 32;
  constexpr int AIT = (BM * 64) / 2048, BIT = (BN * 64) / 2048;
  __shared__ __bf16 As[BM][72];
  __shared__ __bf16 Bs[BN][72];
  int t = threadIdx.x;
  int lane = t & 63, w = t >> 6;
  int lane16 = lane & 15, quad = lane >> 4;
  int wm = (w & 1) * (BM / 2), wn = (w >> 1) * (BN / 2);

  f32x4 acc[MI][JN];
#pragma unroll
  for (int i = 0; i < MI; ++i)
#pragma unroll
    for (int j = 0; j < JN; ++j) acc[i][j] = (f32x4){0.f, 0.f, 0.f, 0.f};

  for (int k0 = kbeg; k0 < kend; k0 += 64) {
#pragma unroll
    for (int i = 0; i < AIT; ++i) {
      int ii = i * 256 + t;
      int m = ii >> 3, kc = (ii & 7) * 8;
      *(bf16x8*)&As[m][kc] = *(const bf16x8*)&A[(size_t)(m0 + m) * K + k0 + kc];
    }
#pragma unroll
    for (int i = 0; i < BIT; ++i) {
      int ii = i * 256 + t;
      int m = ii >> 3, kc = (ii & 7) * 8;
      *(bf16x8*)&Bs[m][kc] = *(const bf16x8*)&Wn[(size_t)(n0 + m) * K + k0 + kc];
    }
    __syncthreads();
#pragma unroll
    for (int kk = 0; kk < 64; kk += 32) {
      bf16x8 af[MI], bfr[JN];
#pragma unroll
      for (int i = 0; i < MI; ++i)
        af[i] = *(const bf16x8*)&As[wm + i * 16 + lane16][kk + quad * 8];
#pragma unroll
      for (int j = 0; j < JN; ++j)
        bfr[j] = *(const bf16x8*)&Bs[wn + j * 16 + lane16][kk + quad * 8];
#pragma unroll
      for (int i = 0; i < MI; ++i)
#pragma unroll
        for (int j = 0; j < JN; ++j)
          acc[i][j] = __builtin_amdgcn_mfma_f32_16x16x32_bf16(af[i], bfr[j], acc[i][j], 0, 0, 0);
    }
    __syncthreads();
  }

#pragma unroll
  for (int j = 0; j < JN; ++j) {
    int col = n0 + wn + j * 16 + lane16;
    float bv = bias ? bias[col] : 0.f;
#pragma unroll
    for (int i = 0; i < MI; ++i) {
#pragma unroll
      for (int r = 0; r < 4; ++r) {
        int row = m0 + wm + i * 16 + quad * 4 + r;
        float v = acc[i][j][r] + bv;
        if (RELU) v = fmaxf(v, 0.f);
        if (OUT_BF16)
          ((__bf16*)outp)[(size_t)row * N + col] = (__bf16)v;
        else
          ((float*)outp)[(size_t)row * N + col] = v;
      }
    }
  }
}

template <int BM, int BN, int RELU, int OUT_BF16>
__global__ __launch_bounds__(256) void k_gemm(
    const __bf16* __restrict__ A, const __bf16* __restrict__ Wn,
    const float* __restrict__ bias, void* __restrict__ outp, int N, int K) {
  gemm_body<BM, BN, RELU, OUT_BF16>(A, Wn, bias, outp,
                                    blockIdx.x * BN, blockIdx.y * BM, N, K, 0, K);
}

// ---- split-K ff2: partials[ks][BQ][C] bf16 (bias added in k_lnt) ----
__global__ __launch_bounds__(256) void k_gemmsk(
    const __bf16* __restrict__ A, const __bf16* __restrict__ Wn,
    __bf16* __restrict__ partials) {
  int ks = blockIdx.z;
  int kbeg = ks * (FF_ / KS_), kend = kbeg + FF_ / KS_;
  gemm_body<128, 128, 0, 1>(A, Wn, nullptr,
                            partials + (size_t)ks * BQ_ * C_,
                            blockIdx.x * 128, blockIdx.y * 128, C_, FF_, kbeg, kend);
}

// ---- split-K o-proj: 2 partials (bias added in k_ln1) ----
__global__ __launch_bounds__(256) void k_gemmsko(
    const __bf16* __restrict__ A, const __bf16* __restrict__ Wn,
    __bf16* __restrict__ partials) {
  int ks = blockIdx.z;
  int kbeg = ks * 128, kend = kbeg + 128;
  gemm_body<128, 64, 0, 1>(A, Wn, nullptr,
                           partials + (size_t)ks * BQ_ * C_,
                           blockIdx.x * 64, blockIdx.y * 128, C_, C_, kbeg, kend);
}

// ---- merged khv GEMM (1024 blocks) + qh GEMM (128 blocks) ----
__global__ __launch_bounds__(256) void k_gemm2(
    const __bf16* __restrict__ keyTb, const __bf16* __restrict__ kvwb,
    __bf16* __restrict__ khvbuf,
    const __bf16* __restrict__ qinb, const __bf16* __restrict__ qwb,
    const float* __restrict__ q_b, __bf16* __restrict__ qhb) {
  int blk = blockIdx.x;
  const __bf16 *A, *Wn; const float* bias; __bf16* outp; int n0, m0, N;
  if (blk < 1024) {
    A = keyTb; Wn = kvwb; bias = nullptr; outp = khvbuf;
    n0 = (blk & 3) * 128; m0 = (blk >> 2) * 128; N = 512;
  } else {
    int l = blk - 1024;
    A = qinb; Wn = qwb; bias = q_b; outp = qhb;
    n0 = (l & 1) * 128; m0 = (l >> 1) * 128; N = 256;
  }
  gemm_body<128, 128, 0, 1>(A, Wn, bias, outp, n0, m0, N, 256, 0, 256);
}

// ---- fused attention (unchanged) ----
__global__ __launch_bounds__(256) void k_attnf(
    const __bf16* __restrict__ khv,
    const float* __restrict__ key_pos,
    const float* __restrict__ query_pos,
    const int* __restrict__ idx,
    const int* __restrict__ maskb,
    const __bf16* __restrict__ qhb,
    const float4* __restrict__ Pk,
    const float4* __restrict__ Pv,
    __bf16* __restrict__ aob) {
  __shared__ __bf16 kvs[S_][520];
  __shared__ float qrow[C_];
  __shared__ float sc[H_][S_];
  __shared__ float pw[H_][S_];
  __shared__ float4 gx4[S_];
  __shared__ float4 pgxs[H_];
  __shared__ float4 qpks[H_];
  __shared__ int srow[S_], smask[S_];
  int bq = blockIdx.x, b = bq >> 10, t = threadIdx.x;

  if (t < S_) {
    int k = idx[(size_t)bq * S_ + t];
    srow[t] = b * NK_ + k;
    smask[t] = maskb[(size_t)bq * S_ + t];
    const float* kpp = key_pos + ((size_t)b * NK_ + k) * 3;
    const float* qp  = query_pos + (size_t)bq * 6;
    gx4[t] = make_float4(kpp[0] - qp[0], kpp[1] - qp[1], kpp[2] - qp[2], 1.f);
  }
  float qv_t = (float)qhb[(size_t)bq * C_ + t];
  qrow[t] = qv_t;
  {
    float4 p = Pk[t];
    p.x *= qv_t; p.y *= qv_t; p.z *= qv_t; p.w *= qv_t;
#pragma unroll
    for (int off = 16; off >= 1; off >>= 1) {
      p.x += __shfl_xor(p.x, off);
      p.y += __shfl_xor(p.y, off);
      p.z += __shfl_xor(p.z, off);
      p.w += __shfl_xor(p.w, off);
    }
    if ((t & 31) == 0) {
      const float s = 0.17677669529663687f;
      qpks[t >> 5] = make_float4(p.x * s, p.y * s, p.z * s, p.w * s);
    }
  }
  __syncthreads();
  {
    int s = t >> 4, c0 = (t & 15) * 32;
    const __bf16* src = khv + (size_t)srow[s] * 512 + c0;
    *(bf16x8*)&kvs[s][c0]      = *(const bf16x8*)&src[0];
    *(bf16x8*)&kvs[s][c0 + 8]  = *(const bf16x8*)&src[8];
    *(bf16x8*)&kvs[s][c0 + 16] = *(const bf16x8*)&src[16];
    *(bf16x8*)&kvs[s][c0 + 24] = *(const bf16x8*)&src[24];
  }
  __syncthreads();
  if (t < H_ * S_) {
    int h = t >> 4, s = t & (S_ - 1);
    float d = 0.f;
#pragma unroll
    for (int c0 = 0; c0 < 32; c0 += 8) {
      bf16x8 xv = *(const bf16x8*)&kvs[s][h * 32 + c0];
#pragma unroll
      for (int j = 0; j < 8; ++j) d += qrow[h * 32 + c0 + j] * (float)xv[j];
    }
    d *= 0.17677669529663687f;
    float4 g = gx4[s];
    float4 pk = qpks[h];
    d += g.x * pk.x + g.y * pk.y + g.z * pk.z + pk.w;
    if (smask[s]) d = -1e30f;
    sc[h][s] = d;
  }
  __syncthreads();
  if (t < H_) {
    float mx = -3.4e38f;
#pragma unroll
    for (int s = 0; s < S_; ++s) mx = fmaxf(mx, sc[t][s]);
    float e[S_], sum = 0.f;
#pragma unroll
    for (int s = 0; s < S_; ++s) { e[s] = expf(sc[t][s] - mx); sum += e[s]; }
    float inv = 1.f / sum;
    float gxx = 0.f, gyy = 0.f, gzz = 0.f;
#pragma unroll
    for (int s = 0; s < S_; ++s) {
      float p = e[s] * inv;
      pw[t][s] = p;
      float4 g = gx4[s];
      gxx += p * g.x; gyy += p * g.y; gzz += p * g.z;
    }
    pgxs[t] = make_float4(gxx, gyy, gzz, 1.f);
  }
  __syncthreads();
  {
    int h = t >> 5;
    float a = 0.f;
#pragma unroll
    for (int s = 0; s < S_; ++s) a += pw[h][s] * (float)kvs[s][256 + t];
    float4 pv = Pv[t];
    float4 g = pgxs[h];
    a += g.x * pv.x + g.y * pv.y + g.z * pv.z + pv.w;
    aob[(size_t)bq * C_ + t] = (__bf16)a;
  }
}

// ---- LN1: x1b = LN(qtokb + op2[0]+op2[1] + o_b)*g + b (bf16 in/out) ----
__global__ __launch_bounds__(256) void k_ln1(const __bf16* __restrict__ xa,
                                             const __bf16* __restrict__ op2,
                                             const float* __restrict__ obias,
                                             const float* __restrict__ g,
                                             const float* __restrict__ bb,
                                             __bf16* __restrict__ outb) {
  int wid = (blockIdx.x * 256 + threadIdx.x) >> 6;
  int lane = threadIdx.x & 63;
  bf16x4 va = *(const bf16x4*)&xa[(size_t)wid * C_ + lane * 4];
  float4 ob4 = *(const float4*)(obias + lane * 4);
  bf16x4 p0 = *(const bf16x4*)&op2[(size_t)wid * C_ + lane * 4];
  bf16x4 p1 = *(const bf16x4*)&op2[(size_t)BQ_ * C_ + (size_t)wid * C_ + lane * 4];
  float x0 = (float)va[0] + ob4.x + (float)p0[0] + (float)p1[0];
  float x1 = (float)va[1] + ob4.y + (float)p0[1] + (float)p1[1];
  float x2 = (float)va[2] + ob4.z + (float)p0[2] + (float)p1[2];
  float x3 = (float)va[3] + ob4.w + (float)p0[3] + (float)p1[3];
  float s = x0 + x1 + x2 + x3;
#pragma unroll
  for (int off = 32; off >= 1; off >>= 1) s += __shfl_xor(s, off);
  float mean = s * (1.f / C_);
  float d0 = x0 - mean, d1 = x1 - mean, d2 = x2 - mean, d3 = x3 - mean;
  float v = d0 * d0 + d1 * d1 + d2 * d2 + d3 * d3;
#pragma unroll
  for (int off = 32; off >= 1; off >>= 1) v += __shfl_xor(v, off);
  float inv = 1.f / sqrtf(v * (1.f / C_) + EPS_);
  float4 g4 = *(const float4*)(g + lane * 4);
  float4 b4 = *(const float4*)(bb + lane * 4);
  __bf16* obp = outb + (size_t)wid * C_ + lane * 4;
  obp[0] = (__bf16)(d0 * inv * g4.x + b4.x);
  obp[1] = (__bf16)(d1 * inv * g4.y + b4.y);
  obp[2] = (__bf16)(d2 * inv * g4.z + b4.z);
  obp[3] = (__bf16)(d3 * inv * g4.w + b4.w);
}

// ---- fused ff2-reduce + LN2 + output transpose (x1 read as bf16) -----------
__global__ __launch_bounds__(256) void k_lnt(const __bf16* __restrict__ x1b,
                                             const __bf16* __restrict__ ff2p,
                                             const float* __restrict__ l2bias,
                                             const float* __restrict__ g,
                                             const float* __restrict__ bb,
                                             float* __restrict__ out) {
  __shared__ float buf[32][257];
  int z = blockIdx.y, nq0 = blockIdx.x * 32;
  int t = threadIdx.x;
  int w = t >> 6, lane = t & 63;
  float4 g4 = *(const float4*)(g + lane * 4);
  float4 b4 = *(const float4*)(bb + lane * 4);
  float4 l2b = *(const float4*)(l2bias + lane * 4);
#pragma unroll
  for (int rr = 0; rr < 8; ++rr) {
    int row = w * 8 + rr;
    size_t grow = (size_t)z * NQ_ + nq0 + row;
    bf16x4 va = *(const bf16x4*)&x1b[grow * C_ + lane * 4];
    float x0 = (float)va[0] + l2b.x, x1 = (float)va[1] + l2b.y;
    float x2 = (float)va[2] + l2b.z, x3 = (float)va[3] + l2b.w;
#pragma unroll
    for (int ks = 0; ks < KS_; ++ks) {
      bf16x4 p = *(const bf16x4*)&ff2p[((size_t)ks * BQ_ + grow) * C_ + lane * 4];
      x0 += (float)p[0]; x1 += (float)p[1]; x2 += (float)p[2]; x3 += (float)p[3];
    }
    float s = x0 + x1 + x2 + x3;
#pragma unroll
    for (int off = 32; off >= 1; off >>= 1) s += __shfl_xor(s, off);
    float mean = s * (1.f / C_);
    float d0 = x0 - mean, d1 = x1 - mean, d2 = x2 - mean, d3 = x3 - mean;
    float v = d0 * d0 + d1 * d1 + d2 * d2 + d3 * d3;
#pragma unroll
    for (int off = 32; off >= 1; off >>= 1) v += __shfl_xor(v, off);
    float inv = 1.f / sqrtf(v * (1.f / C_) + EPS_);
    buf[row][lane * 4 + 0] = d0 * inv * g4.x + b4.x;
    buf[row][lane * 4 + 1] = d1 * inv * g4.y + b4.y;
    buf[row][lane * 4 + 2] = d2 * inv * g4.z + b4.z;
    buf[row][lane * 4 + 3] = d3 * inv * g4.w + b4.w;
  }
  __syncthreads();
  int tx = t & 31, ty = t >> 5;
#pragma unroll
  for (int ci = 0; ci < 32; ++ci) {
    int c = ci * 8 + ty;
    out[((size_t)z * C_ + c) * NQ_ + nq0 + tx] = buf[tx][c];
  }
}

extern "C" void kernel_launch(void* const* d_in, const int* in_sizes, int n_in,
                              void* d_out, int out_size, void* d_ws, size_t ws_size,
                              hipStream_t stream) {
  const float* query     = (const float*)d_in[0];
  const float* key       = (const float*)d_in[1];
  const float* query_pos = (const float*)d_in[2];
  const float* key_pos   = (const float*)d_in[3];
  const float* q_w = (const float*)d_in[4];  const float* q_b = (const float*)d_in[5];
  const float* k_w = (const float*)d_in[6];  const float* k_b = (const float*)d_in[7];
  const float* v_w = (const float*)d_in[8];  const float* v_b = (const float*)d_in[9];
  const float* o_w = (const float*)d_in[10]; const float* o_b = (const float*)d_in[11];
  const float* lin1_w = (const float*)d_in[12]; const float* lin1_b = (const float*)d_in[13];
  const float* lin2_w = (const float*)d_in[14]; const float* lin2_b = (const float*)d_in[15];
  const float* n1_g = (const float*)d_in[16]; const float* n1_b = (const float*)d_in[17];
  const float* n2_g = (const float*)d_in[18]; const float* n2_b = (const float*)d_in[19];
  const float* qpe_w = (const float*)d_in[20]; const float* qpe_b = (const float*)d_in[21];
  const float* kpe_w = (const float*)d_in[22]; const float* kpe_b = (const float*)d_in[23];
  float* out = (float*)d_out;

  const size_t BQc = (size_t)BQ_ * C_;
  float* w = (float*)d_ws;
  size_t o = 0;
  // ---- workspace carve (~115 MB) ----
  __bf16* keyTb = (__bf16*)(w + o); o += (size_t)B_ * NK_ * C_ / 2;   // 16.8 MB
  __bf16* qtokb = (__bf16*)(w + o); o += BQc / 2;
  __bf16* op2  = (__bf16*)(w + o); o += BQc;                          // 2 o-proj partials
  __bf16* khvbuf = (__bf16*)(w + o); o += (size_t)B_ * NK_ * 512 / 2; // 33.5 MB; ff1b overlay
  __bf16* ff2p = (__bf16*)(w + o); o += BQc * KS_ / 2;                // 33.5 MB
  __bf16* qinb = (__bf16*)(w + o); o += BQc / 2;
  __bf16* qhb  = (__bf16*)(w + o); o += BQc / 2;
  __bf16* aob  = (__bf16*)(w + o); o += BQc / 2;
  __bf16* x1b  = (__bf16*)(w + o); o += BQc / 2;
  __bf16* qwb  = (__bf16*)(w + o); o += (size_t)C_ * C_ / 2;
  __bf16* kvwb = (__bf16*)(w + o); o += (size_t)C_ * C_;              // (512,256) = k_w ++ v_w
  __bf16* owb  = (__bf16*)(w + o); o += (size_t)C_ * C_ / 2;
  __bf16* l1b  = (__bf16*)(w + o); o += (size_t)C_ * FF_ / 2;
  __bf16* l2b  = (__bf16*)(w + o); o += (size_t)C_ * FF_ / 2;
  float4* Pk   = (float4*)(w + o); o += C_ * 4;
  float4* Pv   = (float4*)(w + o); o += C_ * 4;
  int* idxb  = (int*)(w + o); o += (size_t)BQ_ * S_;
  int* maskb = (int*)(w + o); o += (size_t)BQ_ * S_;
  __bf16* ff1b = khvbuf;    // khv dead after attnf

  // 1. all preprocessing in one launch (box query first — latency-bound)
  CvtArgs ca;
  ca.src[0] = q_w; ca.dst[0] = qwb;
  ca.src[1] = k_w; ca.dst[1] = kvwb;
  ca.src[2] = v_w; ca.dst[2] = kvwb + (size_t)C_ * C_;
  ca.src[3] = o_w; ca.dst[3] = owb;
  ca.src[4] = lin1_w; ca.dst[4] = l1b;
  ca.src[5] = lin2_w; ca.dst[5] = l2b;
  k_prep<<<NPREP, 256, 0, stream>>>(query, key, query_pos, key_pos,
                                    qpe_w, qpe_b, k_w, k_b, v_w, v_b,
                                    kpe_w, kpe_b, ca,
                                    keyTb, qtokb, qinb, Pk, Pv, idxb, maskb);
  // 2. khv = key_feat @ [k_w|v_w]^T  +  qh = qin @ q_w.T + q_b
  k_gemm2<<<1024 + 128, 256, 0, stream>>>(keyTb, kvwb, khvbuf, qinb, qwb, q_b, qhb);
  // 3. fused attention
  k_attnf<<<BQ_, 256, 0, stream>>>(khvbuf, key_pos, query_pos, idxb, maskb,
                                   qhb, Pk, Pv, aob);
  // 4. o projection split-K=2 -> bf16 partials
  k_gemmsko<<<dim3(C_ / 64, BQ_ / 128, 2), 256, 0, stream>>>(aob, owb, op2);
  // 5. x1b = LN(qtokb + sum(op2) + o_b)  (bf16 residual path)
  k_ln1<<<BQ_ / 4, 256, 0, stream>>>(qtokb, op2, o_b, n1_g, n1_b, x1b);
  // 6. ff1(bf16) = relu(x1b @ lin1.T + b)   [overlays khvbuf]
  k_gemm<128, 128, 1, 1><<<dim3(FF_ / 128, BQ_ / 128), 256, 0, stream>>>(
      x1b, l1b, lin1_b, ff1b, FF_, C_);
  // 7. ff2 split-K: 8 chunks -> bf16 partials
  k_gemmsk<<<dim3(C_ / 128, BQ_ / 128, KS_), 256, 0, stream>>>(ff1b, l2b, ff2p);
  // 8. out = transpose(LN(x1b + sum(ff2p) + lin2_b))
  k_lnt<<<dim3(NQ_ / 32, B_), 256, 0, stream>>>(x1b, ff2p, lin2_b, n2_g, n2_b, out);
}